// Round 3
// baseline (205.861 us; speedup 1.0000x reference)
//
#include <hip/hip_runtime.h>

// GaitPINN: encoder MLP -> 2-D neural ODE (tanh MLP vector field) -> decoder.
// Fixed-step RK4 (85 segments) + cubic Hermite dense output at theta=1/3,2/3
// replaces adaptive dopri5 (absmax 0.016 << 0.079 threshold, measured R1/R2).
// R3: 16 lanes per sample (2 of 32 hidden units each) -> 262144 threads =
// 4096 waves = 4 waves/SIMD (R2 was 2). 16-lane allreduce fully in full-rate
// DPP: xor1, xor2, row_half_mirror, row_mirror. Emit rewritten branch-free:
// lanes 0..4 each own one scalar output stream (zt.a, zt.b, xh.0, xh.1, xh.2)
// via per-lane (ca,cb,cc) coefficients + running pointer.

constexpr int   BATCH = 16384;
constexpr int   NSEG  = 85;
constexpr float DT    = 1.0f / (float)NSEG;
constexpr float DT2   = DT * 0.5f;
constexpr float DT6   = DT / 6.0f;
constexpr float SCALE = 2.8853900817779268f; // 2*log2(e): tanh(s)=1-2/(1+exp2(SCALE*s))

// Cubic Hermite basis at theta=1/3 and 2/3, dt folded into tangent terms
constexpr float A00 = 20.f/27.f, A01 = 7.f/27.f,  A10 = (4.f/27.f)*DT,  A11 = (-2.f/27.f)*DT;
constexpr float B00 = 7.f/27.f,  B01 = 20.f/27.f, B10 = (2.f/27.f)*DT,  B11 = (-4.f/27.f)*DT;

__device__ __forceinline__ float fast_exp2(float x) {
#if __has_builtin(__builtin_amdgcn_exp2f)
  return __builtin_amdgcn_exp2f(x);
#else
  return exp2f(x);
#endif
}

__device__ __forceinline__ float fast_rcp(float x) {
#if __has_builtin(__builtin_amdgcn_rcpf)
  return __builtin_amdgcn_rcpf(x);
#else
  return 1.0f / x;
#endif
}

// v += lane-permuted v, permutation given by DPP ctrl. Full-rate VALU.
template<int CTRL>
__device__ __forceinline__ float dpp_add(float v) {
  int sw = __builtin_amdgcn_update_dpp(0, __float_as_int(v), CTRL, 0xF, 0xF, true);
  return v + __int_as_float(sw);
}

// Butterfly allreduce over each aligned 16-lane group, all full-rate DPP:
// xor1 (quad_perm 0xB1), xor2 (quad_perm 0x4E), row_half_mirror (0x141,
// i<->7-i within 8), row_mirror (0x140, i<->15-i within 16). Step k pairs
// lanes that each hold identical partial sums of complementary subsets, and
// every add is the same commutative pair on both partners -> all 16 lanes
// end bitwise identical.
__device__ __forceinline__ float allred16(float v) {
  v = dpp_add<0xB1>(v);
  v = dpp_add<0x4E>(v);
  v = dpp_add<0x141>(v);
  v = dpp_add<0x140>(v);
  return v;
}

__global__ __launch_bounds__(256) void gait_kernel(
    const float* __restrict__ x,
    const float* __restrict__ We1, const float* __restrict__ be1,
    const float* __restrict__ We2, const float* __restrict__ be2,
    const float* __restrict__ We3, const float* __restrict__ be3,
    const float* __restrict__ Wo1, const float* __restrict__ bo1,
    const float* __restrict__ Wo2, const float* __restrict__ bo2,
    const float* __restrict__ Wd,  const float* __restrict__ bd,
    float* __restrict__ out)
{
  const int t   = blockIdx.x * 256 + threadIdx.x;
  const int b   = t >> 4;   // sample id
  const int sub = t & 15;   // lane within the sample's 16-lane group

  // ---------------- encoder ----------------
  // Layer 1 (9->64): redundant on all 16 lanes (keeps h1 lane-local; ~6% of
  // total issue). Layers 2+3 split 4 columns/lane + DPP allreduce.
  const float* xb = x + (size_t)b * 2304;  // x[b, 0, :], row stride 256*9
  float xv[9];
#pragma unroll
  for (int i = 0; i < 9; ++i) xv[i] = xb[i];

  float h1[64];
#pragma unroll
  for (int j = 0; j < 64; ++j) {
    float s = be1[j];
#pragma unroll
    for (int i = 0; i < 9; ++i) s = fmaf(xv[i], We1[i*64 + j], s);
    h1[j] = fmaxf(s, 0.0f);
  }

  const int c0 = sub * 4;
  float z0a = 0.f, z0b = 0.f;
#pragma unroll
  for (int jj = 0; jj < 4; ++jj) {
    const int j = c0 + jj;
    float s = be2[j];
#pragma unroll
    for (int i = 0; i < 64; ++i) s = fmaf(h1[i], We2[i*64 + j], s);
    s = fmaxf(s, 0.0f);
    z0a = fmaf(s, We3[j*2 + 0], z0a);
    z0b = fmaf(s, We3[j*2 + 1], z0b);
  }
  z0a = allred16(z0a) + be3[0];
  z0b = allred16(z0b) + be3[1];

  // write z0 (out[0 .. 32767]); one lane per sample owns it
  if (sub == 5) {
    float2 v; v.x = z0a; v.y = z0b;
    *reinterpret_cast<float2*>(out + (size_t)b * 2) = v;
  }

  float* __restrict__ zt = out + 32768;             // z_traj (256,16384,2)
  float* __restrict__ xh = out + 32768 + 8388608;   // x_hat  (256,16384,3)

  // ---- branch-free emit setup: lane role sub in [0,5) owns one scalar
  // output stream; val = ca*za + cb*zb + cc; pointer bumped by role stride.
  const float wd0 = Wd[0], wd1 = Wd[1], wd2 = Wd[2];
  const float wd3 = Wd[3], wd4 = Wd[4], wd5 = Wd[5];
  float ca = 0.f, cb = 0.f, cc = 0.f;
  if      (sub == 0) { ca = 1.f; }
  else if (sub == 1) { cb = 1.f; }
  else if (sub == 2) { ca = wd0; cb = wd3; cc = bd[0]; }
  else if (sub == 3) { ca = wd1; cb = wd4; cc = bd[1]; }
  else if (sub == 4) { ca = wd2; cb = wd5; cc = bd[2]; }
  float* p = (sub < 2) ? (zt + (size_t)b * 2 + sub)
                       : (xh + (size_t)b * 3 + (sub - 2));
  const ptrdiff_t pstride = (sub < 2) ? (ptrdiff_t)BATCH * 2 : (ptrdiff_t)BATCH * 3;
  const bool emitter = (sub < 5);

  auto emit = [&](float za, float zb) {
    if (emitter) *p = fmaf(za, ca, fmaf(zb, cb, cc));
    p += pstride;
  };

  // this lane's 2-wide slice of the 32 hidden units of the vector field
  float w1a[2], w1b[2], b1s[2], w2a[2], w2b[2];
  const int u0 = sub * 2;
#pragma unroll
  for (int q = 0; q < 2; ++q) {
    w1a[q] = Wo1[      u0 + q] * SCALE;   // Wo1[0][u]
    w1b[q] = Wo1[32 +  u0 + q] * SCALE;   // Wo1[1][u]
    b1s[q] = bo1[      u0 + q] * SCALE;
    w2a[q] = Wo2[(u0 + q)*2 + 0];
    w2b[q] = Wo2[(u0 + q)*2 + 1];
  }
  const float b20 = bo2[0], b21 = bo2[1];

  // vf(z) = tanh(z@Wo1+bo1)@Wo2+bo2, split over 16 lanes, DPP-allreduced.
  // All 16 lanes end with bitwise-identical (o0,o1) -> replicated state synced.
  auto vf = [&](float za, float zb, float& o0, float& o1) {
    float a0 = 0.f, a1 = 0.f;
#pragma unroll
    for (int q = 0; q < 2; ++q) {
      float u  = fmaf(za, w1a[q], fmaf(zb, w1b[q], b1s[q]));
      float e  = fast_exp2(u);
      float r  = fast_rcp(e + 1.0f);
      float th = fmaf(-2.0f, r, 1.0f);      // tanh
      a0 = fmaf(th, w2a[q], a0);
      a1 = fmaf(th, w2b[q], a1);
    }
    o0 = allred16(a0) + b20;
    o1 = allred16(a1) + b21;
  };

  float za = z0a, zb = z0b;
  float fa, fb;
  vf(za, zb, fa, fb);        // k1 of first segment (carried across segments)
  emit(za, zb);              // m = 0

  for (int k = 0; k < NSEG; ++k) {
    float k2a, k2b, k3a, k3b, k4a, k4b, fna, fnb;
    vf(fmaf(DT2, fa,  za), fmaf(DT2, fb,  zb), k2a, k2b);
    vf(fmaf(DT2, k2a, za), fmaf(DT2, k2b, zb), k3a, k3b);
    vf(fmaf(DT,  k3a, za), fmaf(DT,  k3b, zb), k4a, k4b);
    float zna = fmaf(DT6, fa + k4a + 2.0f*(k2a + k3a), za);
    float znb = fmaf(DT6, fb + k4b + 2.0f*(k2b + k3b), zb);
    vf(zna, znb, fna, fnb);  // next segment's k1 + Hermite end-tangent

    emit(A00*za + A01*zna + A10*fa + A11*fna,    // m = 3k+1 (theta=1/3)
         A00*zb + A01*znb + A10*fb + A11*fnb);
    emit(B00*za + B01*zna + B10*fa + B11*fna,    // m = 3k+2 (theta=2/3)
         B00*zb + B01*znb + B10*fb + B11*fnb);
    emit(zna, znb);                              // m = 3k+3 exact node

    za = zna; zb = znb; fa = fna; fb = fnb;
  }
}

extern "C" void kernel_launch(void* const* d_in, const int* in_sizes, int n_in,
                              void* d_out, int out_size, void* d_ws, size_t ws_size,
                              hipStream_t stream)
{
  const float* x   = (const float*)d_in[0];
  const float* We1 = (const float*)d_in[1];
  const float* be1 = (const float*)d_in[2];
  const float* We2 = (const float*)d_in[3];
  const float* be2 = (const float*)d_in[4];
  const float* We3 = (const float*)d_in[5];
  const float* be3 = (const float*)d_in[6];
  const float* Wo1 = (const float*)d_in[7];
  const float* bo1 = (const float*)d_in[8];
  const float* Wo2 = (const float*)d_in[9];
  const float* bo2 = (const float*)d_in[10];
  const float* Wd  = (const float*)d_in[11];
  const float* bd  = (const float*)d_in[12];

  dim3 grid(BATCH * 16 / 256), block(256);
  gait_kernel<<<grid, block, 0, stream>>>(x, We1, be1, We2, be2, We3, be3,
                                          Wo1, bo1, Wo2, bo2, Wd, bd,
                                          (float*)d_out);
}

// Round 4
// 123.989 us; speedup vs baseline: 1.6603x; 1.6603x over previous
//
#include <hip/hip_runtime.h>

// GaitPINN: encoder MLP -> 2-D neural ODE (tanh MLP vector field) -> decoder.
// Fixed-step RK4 (85 segments) + cubic Hermite dense output at theta=1/3,2/3
// replaces adaptive dopri5 (absmax 0.016 << 0.079 threshold, measured R1-R3).
// R4: keep R3's 16 lanes/sample (4 waves/SIMD target) but pin codegen:
//   - #pragma unroll 1 on the NSEG loop (R3's VGPR 52->156 blowup + I-cache
//     thrash came from compiler unroll/pipelining of the 85-iter loop)
//   - loop-interchanged encoder (no h1[64] array: ~15 live VGPRs instead of 64)

constexpr int   BATCH = 16384;
constexpr int   NSEG  = 85;
constexpr float DT    = 1.0f / (float)NSEG;
constexpr float DT2   = DT * 0.5f;
constexpr float DT6   = DT / 6.0f;
constexpr float SCALE = 2.8853900817779268f; // 2*log2(e): tanh(s)=1-2/(1+exp2(SCALE*s))

// Cubic Hermite basis at theta=1/3 and 2/3, dt folded into tangent terms
constexpr float A00 = 20.f/27.f, A01 = 7.f/27.f,  A10 = (4.f/27.f)*DT,  A11 = (-2.f/27.f)*DT;
constexpr float B00 = 7.f/27.f,  B01 = 20.f/27.f, B10 = (2.f/27.f)*DT,  B11 = (-4.f/27.f)*DT;

__device__ __forceinline__ float fast_exp2(float x) {
#if __has_builtin(__builtin_amdgcn_exp2f)
  return __builtin_amdgcn_exp2f(x);
#else
  return exp2f(x);
#endif
}

__device__ __forceinline__ float fast_rcp(float x) {
#if __has_builtin(__builtin_amdgcn_rcpf)
  return __builtin_amdgcn_rcpf(x);
#else
  return 1.0f / x;
#endif
}

// v += lane-permuted v, permutation given by DPP ctrl. Full-rate VALU.
template<int CTRL>
__device__ __forceinline__ float dpp_add(float v) {
  int sw = __builtin_amdgcn_update_dpp(0, __float_as_int(v), CTRL, 0xF, 0xF, true);
  return v + __int_as_float(sw);
}

// Butterfly allreduce over each aligned 16-lane group, all full-rate DPP:
// xor1 (quad_perm 0xB1), xor2 (quad_perm 0x4E), row_half_mirror (0x141,
// i<->7-i within 8), row_mirror (0x140, i<->15-i within 16). Every step adds
// the same commutative pair on both partners -> all 16 lanes end bitwise
// identical (verified: R2/R3 benches passed with identical absmax).
__device__ __forceinline__ float allred16(float v) {
  v = dpp_add<0xB1>(v);
  v = dpp_add<0x4E>(v);
  v = dpp_add<0x141>(v);
  v = dpp_add<0x140>(v);
  return v;
}

__global__ __launch_bounds__(256) void gait_kernel(
    const float* __restrict__ x,
    const float* __restrict__ We1, const float* __restrict__ be1,
    const float* __restrict__ We2, const float* __restrict__ be2,
    const float* __restrict__ We3, const float* __restrict__ be3,
    const float* __restrict__ Wo1, const float* __restrict__ bo1,
    const float* __restrict__ Wo2, const float* __restrict__ bo2,
    const float* __restrict__ Wd,  const float* __restrict__ bd,
    float* __restrict__ out)
{
  const int t   = blockIdx.x * 256 + threadIdx.x;
  const int b   = t >> 4;   // sample id
  const int sub = t & 15;   // lane within the sample's 16-lane group

  // ---------------- encoder, loop-interchanged ----------------
  // Each lane owns 4 columns of layer 2. h1[i] is computed on the fly and
  // consumed immediately -> no 64-wide live array.
  const float* xb = x + (size_t)b * 2304;  // x[b, 0, :], row stride 256*9
  float xv[9];
#pragma unroll
  for (int i = 0; i < 9; ++i) xv[i] = xb[i];

  const int c0 = sub * 4;
  float s0 = be2[c0+0], s1 = be2[c0+1], s2 = be2[c0+2], s3 = be2[c0+3];
#pragma unroll 4
  for (int i = 0; i < 64; ++i) {
    float h = be1[i];
#pragma unroll
    for (int j = 0; j < 9; ++j) h = fmaf(xv[j], We1[j*64 + i], h);
    h = fmaxf(h, 0.0f);
    const float* w2r = We2 + i*64 + c0;
    s0 = fmaf(h, w2r[0], s0);
    s1 = fmaf(h, w2r[1], s1);
    s2 = fmaf(h, w2r[2], s2);
    s3 = fmaf(h, w2r[3], s3);
  }
  s0 = fmaxf(s0, 0.0f); s1 = fmaxf(s1, 0.0f);
  s2 = fmaxf(s2, 0.0f); s3 = fmaxf(s3, 0.0f);
  float z0a = fmaf(s0, We3[(c0+0)*2+0], fmaf(s1, We3[(c0+1)*2+0],
              fmaf(s2, We3[(c0+2)*2+0],      s3 * We3[(c0+3)*2+0])));
  float z0b = fmaf(s0, We3[(c0+0)*2+1], fmaf(s1, We3[(c0+1)*2+1],
              fmaf(s2, We3[(c0+2)*2+1],      s3 * We3[(c0+3)*2+1])));
  z0a = allred16(z0a) + be3[0];
  z0b = allred16(z0b) + be3[1];

  // write z0 (out[0 .. 32767]); one lane per sample owns it
  if (sub == 5) {
    float2 v; v.x = z0a; v.y = z0b;
    *reinterpret_cast<float2*>(out + (size_t)b * 2) = v;
  }

  float* __restrict__ zt = out + 32768;             // z_traj (256,16384,2)
  float* __restrict__ xh = out + 32768 + 8388608;   // x_hat  (256,16384,3)

  // ---- branch-free emit: lane role sub in [0,5) owns one scalar output
  // stream; val = ca*za + cb*zb + cc; pointer bumped by per-role stride.
  float ca = 0.f, cb = 0.f, cc = 0.f;
  if      (sub == 0) { ca = 1.f; }
  else if (sub == 1) { cb = 1.f; }
  else if (sub == 2) { ca = Wd[0]; cb = Wd[3]; cc = bd[0]; }
  else if (sub == 3) { ca = Wd[1]; cb = Wd[4]; cc = bd[1]; }
  else if (sub == 4) { ca = Wd[2]; cb = Wd[5]; cc = bd[2]; }
  float* p = (sub < 2) ? (zt + (size_t)b * 2 + sub)
                       : (xh + (size_t)b * 3 + (sub - 2));
  const ptrdiff_t pstride = (sub < 2) ? (ptrdiff_t)BATCH * 2 : (ptrdiff_t)BATCH * 3;
  const bool emitter = (sub < 5);

  auto emit = [&](float za, float zb) {
    if (emitter) *p = fmaf(za, ca, fmaf(zb, cb, cc));
    p += pstride;
  };

  // this lane's 2-wide slice of the 32 hidden units of the vector field
  float w1a[2], w1b[2], b1s[2], w2a[2], w2b[2];
  const int u0 = sub * 2;
#pragma unroll
  for (int q = 0; q < 2; ++q) {
    w1a[q] = Wo1[      u0 + q] * SCALE;   // Wo1[0][u]
    w1b[q] = Wo1[32 +  u0 + q] * SCALE;   // Wo1[1][u]
    b1s[q] = bo1[      u0 + q] * SCALE;
    w2a[q] = Wo2[(u0 + q)*2 + 0];
    w2b[q] = Wo2[(u0 + q)*2 + 1];
  }
  const float b20 = bo2[0], b21 = bo2[1];

  // vf(z) = tanh(z@Wo1+bo1)@Wo2+bo2, split over 16 lanes, DPP-allreduced.
  // All 16 lanes end with bitwise-identical (o0,o1) -> replicated state synced.
  auto vf = [&](float za, float zb, float& o0, float& o1) {
    float a0 = 0.f, a1 = 0.f;
#pragma unroll
    for (int q = 0; q < 2; ++q) {
      float u  = fmaf(za, w1a[q], fmaf(zb, w1b[q], b1s[q]));
      float e  = fast_exp2(u);
      float r  = fast_rcp(e + 1.0f);
      float th = fmaf(-2.0f, r, 1.0f);      // tanh
      a0 = fmaf(th, w2a[q], a0);
      a1 = fmaf(th, w2b[q], a1);
    }
    o0 = allred16(a0) + b20;
    o1 = allred16(a1) + b21;
  };

  float za = z0a, zb = z0b;
  float fa, fb;
  vf(za, zb, fa, fb);        // k1 of first segment (carried across segments)
  emit(za, zb);              // m = 0

  // R4: forbid unrolling — R3's compiler unroll of this loop exploded VGPRs
  // (52 -> 156) and thrashed L1I, dropping occupancy below 3 waves/SIMD.
#pragma unroll 1
  for (int k = 0; k < NSEG; ++k) {
    float k2a, k2b, k3a, k3b, k4a, k4b, fna, fnb;
    vf(fmaf(DT2, fa,  za), fmaf(DT2, fb,  zb), k2a, k2b);
    vf(fmaf(DT2, k2a, za), fmaf(DT2, k2b, zb), k3a, k3b);
    vf(fmaf(DT,  k3a, za), fmaf(DT,  k3b, zb), k4a, k4b);
    float zna = fmaf(DT6, fa + k4a + 2.0f*(k2a + k3a), za);
    float znb = fmaf(DT6, fb + k4b + 2.0f*(k2b + k3b), zb);
    vf(zna, znb, fna, fnb);  // next segment's k1 + Hermite end-tangent

    emit(A00*za + A01*zna + A10*fa + A11*fna,    // m = 3k+1 (theta=1/3)
         A00*zb + A01*znb + A10*fb + A11*fnb);
    emit(B00*za + B01*zna + B10*fa + B11*fna,    // m = 3k+2 (theta=2/3)
         B00*zb + B01*znb + B10*fb + B11*fnb);
    emit(zna, znb);                              // m = 3k+3 exact node

    za = zna; zb = znb; fa = fna; fb = fnb;
  }
}

extern "C" void kernel_launch(void* const* d_in, const int* in_sizes, int n_in,
                              void* d_out, int out_size, void* d_ws, size_t ws_size,
                              hipStream_t stream)
{
  const float* x   = (const float*)d_in[0];
  const float* We1 = (const float*)d_in[1];
  const float* be1 = (const float*)d_in[2];
  const float* We2 = (const float*)d_in[3];
  const float* be2 = (const float*)d_in[4];
  const float* We3 = (const float*)d_in[5];
  const float* be3 = (const float*)d_in[6];
  const float* Wo1 = (const float*)d_in[7];
  const float* bo1 = (const float*)d_in[8];
  const float* Wo2 = (const float*)d_in[9];
  const float* bo2 = (const float*)d_in[10];
  const float* Wd  = (const float*)d_in[11];
  const float* bd  = (const float*)d_in[12];

  dim3 grid(BATCH * 16 / 256), block(256);
  gait_kernel<<<grid, block, 0, stream>>>(x, We1, be1, We2, be2, We3, be3,
                                          Wo1, bo1, Wo2, bo2, Wd, bd,
                                          (float*)d_out);
}

// Round 5
// 83.285 us; speedup vs baseline: 2.4718x; 1.4887x over previous
//
#include <hip/hip_runtime.h>

// GaitPINN: encoder MLP -> 2-D neural ODE (tanh MLP vector field) -> decoder.
// Fixed-step RK4 + cubic Hermite dense output replaces adaptive dopri5.
// R5: NSEG 85->51 with 5 outputs/segment (theta=0.2,0.4,0.6,0.8 + node).
// vf evals 341->205. Error budget: our RK4 truncation ~1.3e-3 at dt=1/51;
// measured absmax 0.0156 (R1-R4, integrator-insensitive -> reference-noise
// dominated) + 1.3e-3 << 0.079 threshold.
// Keeps R4's pinned codegen: #pragma unroll 1 main loop (R3 lesson: compiler
// unroll exploded VGPR 52->156), loop-interchanged encoder, 16 lanes/sample
// (4 waves/SIMD), full-DPP 16-lane allreduce, branch-free role-based emit.

constexpr int   BATCH = 16384;
constexpr int   NSEG  = 51;
constexpr float DT    = 1.0f / (float)NSEG;
constexpr float DT2   = DT * 0.5f;
constexpr float DT6   = DT / 6.0f;
constexpr float SCALE = 2.8853900817779268f; // 2*log2(e): tanh(s)=1-2/(1+exp2(SCALE*s))

// Cubic Hermite basis at theta = j/5, j=1..4 (tangent terms carry *DT):
// h00=2t^3-3t^2+1, h01=-2t^3+3t^2, h10=t^3-2t^2+t, h11=t^3-t^2
__device__ __constant__ float H00[4] = {0.896f, 0.648f, 0.352f, 0.104f};
__device__ __constant__ float H01[4] = {0.104f, 0.352f, 0.648f, 0.896f};
__device__ __constant__ float H10[4] = { 0.128f*DT,  0.144f*DT,  0.096f*DT,  0.032f*DT};
__device__ __constant__ float H11[4] = {-0.032f*DT, -0.096f*DT, -0.144f*DT, -0.128f*DT};

__device__ __forceinline__ float fast_exp2(float x) {
#if __has_builtin(__builtin_amdgcn_exp2f)
  return __builtin_amdgcn_exp2f(x);
#else
  return exp2f(x);
#endif
}

__device__ __forceinline__ float fast_rcp(float x) {
#if __has_builtin(__builtin_amdgcn_rcpf)
  return __builtin_amdgcn_rcpf(x);
#else
  return 1.0f / x;
#endif
}

// v += lane-permuted v, permutation given by DPP ctrl. Full-rate VALU.
template<int CTRL>
__device__ __forceinline__ float dpp_add(float v) {
  int sw = __builtin_amdgcn_update_dpp(0, __float_as_int(v), CTRL, 0xF, 0xF, true);
  return v + __int_as_float(sw);
}

// Butterfly allreduce over each aligned 16-lane group, all full-rate DPP:
// xor1 (quad_perm 0xB1), xor2 (quad_perm 0x4E), row_half_mirror (0x141),
// row_mirror (0x140). Every step adds the same commutative pair on both
// partners -> all 16 lanes end bitwise identical (verified R2-R4).
__device__ __forceinline__ float allred16(float v) {
  v = dpp_add<0xB1>(v);
  v = dpp_add<0x4E>(v);
  v = dpp_add<0x141>(v);
  v = dpp_add<0x140>(v);
  return v;
}

__global__ __launch_bounds__(256) void gait_kernel(
    const float* __restrict__ x,
    const float* __restrict__ We1, const float* __restrict__ be1,
    const float* __restrict__ We2, const float* __restrict__ be2,
    const float* __restrict__ We3, const float* __restrict__ be3,
    const float* __restrict__ Wo1, const float* __restrict__ bo1,
    const float* __restrict__ Wo2, const float* __restrict__ bo2,
    const float* __restrict__ Wd,  const float* __restrict__ bd,
    float* __restrict__ out)
{
  const int t   = blockIdx.x * 256 + threadIdx.x;
  const int b   = t >> 4;   // sample id
  const int sub = t & 15;   // lane within the sample's 16-lane group

  // ---------------- encoder, loop-interchanged (R4) ----------------
  const float* xb = x + (size_t)b * 2304;  // x[b, 0, :], row stride 256*9
  float xv[9];
#pragma unroll
  for (int i = 0; i < 9; ++i) xv[i] = xb[i];

  const int c0 = sub * 4;
  float s0 = be2[c0+0], s1 = be2[c0+1], s2 = be2[c0+2], s3 = be2[c0+3];
#pragma unroll 4
  for (int i = 0; i < 64; ++i) {
    float h = be1[i];
#pragma unroll
    for (int j = 0; j < 9; ++j) h = fmaf(xv[j], We1[j*64 + i], h);
    h = fmaxf(h, 0.0f);
    const float* w2r = We2 + i*64 + c0;
    s0 = fmaf(h, w2r[0], s0);
    s1 = fmaf(h, w2r[1], s1);
    s2 = fmaf(h, w2r[2], s2);
    s3 = fmaf(h, w2r[3], s3);
  }
  s0 = fmaxf(s0, 0.0f); s1 = fmaxf(s1, 0.0f);
  s2 = fmaxf(s2, 0.0f); s3 = fmaxf(s3, 0.0f);
  float z0a = fmaf(s0, We3[(c0+0)*2+0], fmaf(s1, We3[(c0+1)*2+0],
              fmaf(s2, We3[(c0+2)*2+0],      s3 * We3[(c0+3)*2+0])));
  float z0b = fmaf(s0, We3[(c0+0)*2+1], fmaf(s1, We3[(c0+1)*2+1],
              fmaf(s2, We3[(c0+2)*2+1],      s3 * We3[(c0+3)*2+1])));
  z0a = allred16(z0a) + be3[0];
  z0b = allred16(z0b) + be3[1];

  // write z0 (out[0 .. 32767]); one lane per sample owns it
  if (sub == 5) {
    float2 v; v.x = z0a; v.y = z0b;
    *reinterpret_cast<float2*>(out + (size_t)b * 2) = v;
  }

  float* __restrict__ zt = out + 32768;             // z_traj (256,16384,2)
  float* __restrict__ xh = out + 32768 + 8388608;   // x_hat  (256,16384,3)

  // ---- branch-free emit: lane role sub in [0,5) owns one scalar output
  // stream; val = ca*za + cb*zb + cc; pointer bumped by per-role stride.
  float ca = 0.f, cb = 0.f, cc = 0.f;
  if      (sub == 0) { ca = 1.f; }
  else if (sub == 1) { cb = 1.f; }
  else if (sub == 2) { ca = Wd[0]; cb = Wd[3]; cc = bd[0]; }
  else if (sub == 3) { ca = Wd[1]; cb = Wd[4]; cc = bd[1]; }
  else if (sub == 4) { ca = Wd[2]; cb = Wd[5]; cc = bd[2]; }
  float* p = (sub < 2) ? (zt + (size_t)b * 2 + sub)
                       : (xh + (size_t)b * 3 + (sub - 2));
  const ptrdiff_t pstride = (sub < 2) ? (ptrdiff_t)BATCH * 2 : (ptrdiff_t)BATCH * 3;
  const bool emitter = (sub < 5);

  auto emit = [&](float za, float zb) {
    if (emitter) *p = fmaf(za, ca, fmaf(zb, cb, cc));
    p += pstride;
  };

  // this lane's 2-wide slice of the 32 hidden units of the vector field
  float w1a[2], w1b[2], b1s[2], w2a[2], w2b[2];
  const int u0 = sub * 2;
#pragma unroll
  for (int q = 0; q < 2; ++q) {
    w1a[q] = Wo1[      u0 + q] * SCALE;   // Wo1[0][u]
    w1b[q] = Wo1[32 +  u0 + q] * SCALE;   // Wo1[1][u]
    b1s[q] = bo1[      u0 + q] * SCALE;
    w2a[q] = Wo2[(u0 + q)*2 + 0];
    w2b[q] = Wo2[(u0 + q)*2 + 1];
  }
  const float b20 = bo2[0], b21 = bo2[1];

  // vf(z) = tanh(z@Wo1+bo1)@Wo2+bo2, split over 16 lanes, DPP-allreduced.
  // All 16 lanes end with bitwise-identical (o0,o1) -> replicated state synced.
  auto vf = [&](float za, float zb, float& o0, float& o1) {
    float a0 = 0.f, a1 = 0.f;
#pragma unroll
    for (int q = 0; q < 2; ++q) {
      float u  = fmaf(za, w1a[q], fmaf(zb, w1b[q], b1s[q]));
      float e  = fast_exp2(u);
      float r  = fast_rcp(e + 1.0f);
      float th = fmaf(-2.0f, r, 1.0f);      // tanh
      a0 = fmaf(th, w2a[q], a0);
      a1 = fmaf(th, w2b[q], a1);
    }
    o0 = allred16(a0) + b20;
    o1 = allred16(a1) + b21;
  };

  float za = z0a, zb = z0b;
  float fa, fb;
  vf(za, zb, fa, fb);        // k1 of first segment (carried across segments)
  emit(za, zb);              // m = 0

  // #pragma unroll 1: R3 lesson — compiler unroll of this loop exploded
  // VGPRs (52->156) and thrashed L1I.
#pragma unroll 1
  for (int k = 0; k < NSEG; ++k) {
    float k2a, k2b, k3a, k3b, k4a, k4b, fna, fnb;
    vf(fmaf(DT2, fa,  za), fmaf(DT2, fb,  zb), k2a, k2b);
    vf(fmaf(DT2, k2a, za), fmaf(DT2, k2b, zb), k3a, k3b);
    vf(fmaf(DT,  k3a, za), fmaf(DT,  k3b, zb), k4a, k4b);
    float zna = fmaf(DT6, fa + k4a + 2.0f*(k2a + k3a), za);
    float znb = fmaf(DT6, fb + k4b + 2.0f*(k2b + k3b), zb);
    vf(zna, znb, fna, fnb);  // next segment's k1 + Hermite end-tangent

    // 4 Hermite interpolants (m = 5k+1 .. 5k+4), then the exact node (5k+5)
#pragma unroll
    for (int j = 0; j < 4; ++j) {
      emit(fmaf(H00[j], za, fmaf(H01[j], zna, fmaf(H10[j], fa, H11[j]*fna))),
           fmaf(H00[j], zb, fmaf(H01[j], znb, fmaf(H10[j], fb, H11[j]*fnb))));
    }
    emit(zna, znb);          // k=50 -> m=255 (t=1), exact node

    za = zna; zb = znb; fa = fna; fb = fnb;
  }
}

extern "C" void kernel_launch(void* const* d_in, const int* in_sizes, int n_in,
                              void* d_out, int out_size, void* d_ws, size_t ws_size,
                              hipStream_t stream)
{
  const float* x   = (const float*)d_in[0];
  const float* We1 = (const float*)d_in[1];
  const float* be1 = (const float*)d_in[2];
  const float* We2 = (const float*)d_in[3];
  const float* be2 = (const float*)d_in[4];
  const float* We3 = (const float*)d_in[5];
  const float* be3 = (const float*)d_in[6];
  const float* Wo1 = (const float*)d_in[7];
  const float* bo1 = (const float*)d_in[8];
  const float* Wo2 = (const float*)d_in[9];
  const float* bo2 = (const float*)d_in[10];
  const float* Wd  = (const float*)d_in[11];
  const float* bd  = (const float*)d_in[12];

  dim3 grid(BATCH * 16 / 256), block(256);
  gait_kernel<<<grid, block, 0, stream>>>(x, We1, be1, We2, be2, We3, be3,
                                          Wo1, bo1, Wo2, bo2, Wd, bd,
                                          (float*)d_out);
}

// Round 6
// 59.051 us; speedup vs baseline: 3.4862x; 1.4104x over previous
//
#include <hip/hip_runtime.h>

// GaitPINN: encoder MLP -> 2-D neural ODE (tanh MLP vector field) -> decoder.
// Fixed-step RK4 + cubic dense output replaces adaptive dopri5.
// R6: (a) output grid decoupled from step grid via power-basis cubic Hermite
//     (coeffs once per segment, 3-FMA Horner per output) -> NSEG drops 51->32
//     (vf evals 205->129). RK4 truncation ~8e-3, absmax budget 0.016+0.008
//     << 0.079.
//     (b) emit spread over 15 lanes (role=sub%5, slot=sub/5, 3 passes) instead
//     of 5 serial emitter lanes -> wave-issue per segment for emit ~42 vs ~80.
// Keeps R4/R5 pinned codegen: #pragma unroll 1 main loop (R3: compiler unroll
// blew VGPR 52->156), interchanged encoder, 16 lanes/sample, full-DPP allred16.

constexpr int   BATCH = 16384;
constexpr int   NSEG  = 32;
constexpr float DT    = 1.0f / (float)NSEG;
constexpr float DT2   = DT * 0.5f;
constexpr float DT6   = DT / 6.0f;
constexpr float SCALE = 2.8853900817779268f; // 2*log2(e): tanh(s)=1-2/(1+exp2(SCALE*s))
constexpr float K255  = 32.0f / 255.0f;      // theta = m*K255 - k

__device__ __forceinline__ float fast_exp2(float x) {
#if __has_builtin(__builtin_amdgcn_exp2f)
  return __builtin_amdgcn_exp2f(x);
#else
  return exp2f(x);
#endif
}

__device__ __forceinline__ float fast_rcp(float x) {
#if __has_builtin(__builtin_amdgcn_rcpf)
  return __builtin_amdgcn_rcpf(x);
#else
  return 1.0f / x;
#endif
}

// v += lane-permuted v, permutation given by DPP ctrl. Full-rate VALU.
template<int CTRL>
__device__ __forceinline__ float dpp_add(float v) {
  int sw = __builtin_amdgcn_update_dpp(0, __float_as_int(v), CTRL, 0xF, 0xF, true);
  return v + __int_as_float(sw);
}

// Butterfly allreduce over each aligned 16-lane group, all full-rate DPP:
// xor1 (quad_perm 0xB1), xor2 (quad_perm 0x4E), row_half_mirror (0x141),
// row_mirror (0x140). All 16 lanes end bitwise identical (verified R2-R5).
__device__ __forceinline__ float allred16(float v) {
  v = dpp_add<0xB1>(v);
  v = dpp_add<0x4E>(v);
  v = dpp_add<0x141>(v);
  v = dpp_add<0x140>(v);
  return v;
}

__global__ __launch_bounds__(256) void gait_kernel(
    const float* __restrict__ x,
    const float* __restrict__ We1, const float* __restrict__ be1,
    const float* __restrict__ We2, const float* __restrict__ be2,
    const float* __restrict__ We3, const float* __restrict__ be3,
    const float* __restrict__ Wo1, const float* __restrict__ bo1,
    const float* __restrict__ Wo2, const float* __restrict__ bo2,
    const float* __restrict__ Wd,  const float* __restrict__ bd,
    float* __restrict__ out)
{
  const int t   = blockIdx.x * 256 + threadIdx.x;
  const int b   = t >> 4;   // sample id
  const int sub = t & 15;   // lane within the sample's 16-lane group

  // ---------------- encoder, loop-interchanged (R4) ----------------
  const float* xb = x + (size_t)b * 2304;  // x[b, 0, :], row stride 256*9
  float xv[9];
#pragma unroll
  for (int i = 0; i < 9; ++i) xv[i] = xb[i];

  const int c0 = sub * 4;
  float s0 = be2[c0+0], s1 = be2[c0+1], s2 = be2[c0+2], s3 = be2[c0+3];
#pragma unroll 4
  for (int i = 0; i < 64; ++i) {
    float h = be1[i];
#pragma unroll
    for (int j = 0; j < 9; ++j) h = fmaf(xv[j], We1[j*64 + i], h);
    h = fmaxf(h, 0.0f);
    const float* w2r = We2 + i*64 + c0;
    s0 = fmaf(h, w2r[0], s0);
    s1 = fmaf(h, w2r[1], s1);
    s2 = fmaf(h, w2r[2], s2);
    s3 = fmaf(h, w2r[3], s3);
  }
  s0 = fmaxf(s0, 0.0f); s1 = fmaxf(s1, 0.0f);
  s2 = fmaxf(s2, 0.0f); s3 = fmaxf(s3, 0.0f);
  float z0a = fmaf(s0, We3[(c0+0)*2+0], fmaf(s1, We3[(c0+1)*2+0],
              fmaf(s2, We3[(c0+2)*2+0],      s3 * We3[(c0+3)*2+0])));
  float z0b = fmaf(s0, We3[(c0+0)*2+1], fmaf(s1, We3[(c0+1)*2+1],
              fmaf(s2, We3[(c0+2)*2+1],      s3 * We3[(c0+3)*2+1])));
  z0a = allred16(z0a) + be3[0];
  z0b = allred16(z0b) + be3[1];

  // write z0 (out[0 .. 32767]); one lane per sample owns it
  if (sub == 5) {
    float2 v; v.x = z0a; v.y = z0b;
    *reinterpret_cast<float2*>(out + (size_t)b * 2) = v;
  }

  float* __restrict__ zt = out + 32768;             // z_traj (256,16384,2)
  float* __restrict__ xh = out + 32768 + 8388608;   // x_hat  (256,16384,3)

  // ---- spread emit setup: role r = sub%5 picks the output scalar
  // (zt.a, zt.b, xh.0, xh.1, xh.2); slot0 = sub/5 picks the time sub-slot.
  // Lane 15 (slot0=3, r=0) is masked off. val = ca*va + cb*vb + cc.
  const int r     = sub % 5;
  const int slot0 = sub / 5;
  const bool emit_active = (sub < 15);
  float ca = 0.f, cb = 0.f, cc = 0.f;
  if      (r == 0) { ca = 1.f; }
  else if (r == 1) { cb = 1.f; }
  else if (r == 2) { ca = Wd[0]; cb = Wd[3]; cc = bd[0]; }
  else if (r == 3) { ca = Wd[1]; cb = Wd[4]; cc = bd[1]; }
  else             { ca = Wd[2]; cb = Wd[5]; cc = bd[2]; }
  float* pbase = (r < 2) ? (zt + (size_t)b * 2 + r)
                         : (xh + (size_t)b * 3 + (r - 2));
  const size_t pstride = (r < 2) ? (size_t)BATCH * 2 : (size_t)BATCH * 3;

  // m = 0 output (theta=0 of segment 0): roles 0..4 live on lanes 0..4
  if (sub < 5) pbase[0] = fmaf(z0a, ca, fmaf(z0b, cb, cc));

  // this lane's 2-wide slice of the 32 hidden units of the vector field
  float w1a[2], w1b[2], b1s[2], w2a[2], w2b[2];
  const int u0 = sub * 2;
#pragma unroll
  for (int q = 0; q < 2; ++q) {
    w1a[q] = Wo1[      u0 + q] * SCALE;   // Wo1[0][u]
    w1b[q] = Wo1[32 +  u0 + q] * SCALE;   // Wo1[1][u]
    b1s[q] = bo1[      u0 + q] * SCALE;
    w2a[q] = Wo2[(u0 + q)*2 + 0];
    w2b[q] = Wo2[(u0 + q)*2 + 1];
  }
  const float b20 = bo2[0], b21 = bo2[1];

  // vf(z) = tanh(z@Wo1+bo1)@Wo2+bo2, split over 16 lanes, DPP-allreduced.
  // All 16 lanes end with bitwise-identical (o0,o1) (verified R2-R5).
  auto vf = [&](float za, float zb, float& o0, float& o1) {
    float a0 = 0.f, a1 = 0.f;
#pragma unroll
    for (int q = 0; q < 2; ++q) {
      float u  = fmaf(za, w1a[q], fmaf(zb, w1b[q], b1s[q]));
      float e  = fast_exp2(u);
      float rr = fast_rcp(e + 1.0f);
      float th = fmaf(-2.0f, rr, 1.0f);     // tanh
      a0 = fmaf(th, w2a[q], a0);
      a1 = fmaf(th, w2b[q], a1);
    }
    o0 = allred16(a0) + b20;
    o1 = allred16(a1) + b21;
  };

  float za = z0a, zb = z0b;
  float fa, fb;
  vf(za, zb, fa, fb);        // k1 of first segment (carried across segments)

  // #pragma unroll 1: R3 lesson — compiler unroll of this loop exploded
  // VGPRs (52->156) and thrashed L1I.
#pragma unroll 1
  for (int k = 0; k < NSEG; ++k) {
    float k2a, k2b, k3a, k3b, k4a, k4b, fna, fnb;
    vf(fmaf(DT2, fa,  za), fmaf(DT2, fb,  zb), k2a, k2b);
    vf(fmaf(DT2, k2a, za), fmaf(DT2, k2b, zb), k3a, k3b);
    vf(fmaf(DT,  k3a, za), fmaf(DT,  k3b, zb), k4a, k4b);
    float zna = fmaf(DT6, fa + k4a + 2.0f*(k2a + k3a), za);
    float znb = fmaf(DT6, fb + k4b + 2.0f*(k2b + k3b), zb);
    vf(zna, znb, fna, fnb);  // next segment's k1 + Hermite end-tangent

    // Dense output: cubic Hermite in power basis, p(th)=((c3*th+c2)*th+c1)*th+c0
    // with c0=z, c1=dt*f, c2=3d-2c1-dt*fn, c3=-2d+c1+dt*fn, d=zn-z.
    const float fadt  = DT * fa,  fbdt  = DT * fb;
    const float fnadt = DT * fna, fnbdt = DT * fnb;
    const float da = zna - za,    db = znb - zb;
    const float c2a = fmaf(3.f, da, -fmaf(2.f, fadt, fnadt));
    const float c3a = fmaf(-2.f, da, fadt + fnadt);
    const float c2b = fmaf(3.f, db, -fmaf(2.f, fbdt, fnbdt));
    const float c3b = fmaf(-2.f, db, fbdt + fnbdt);

    // outputs m with t_m = m/255 in (k/32, (k+1)/32]
    const int m0    = ((255 * k) >> 5) + 1;
    const int mlast = (255 * (k + 1)) >> 5;   // 7 or 8 outputs per segment
    const float kneg = -(float)k;
#pragma unroll
    for (int pass = 0; pass < 3; ++pass) {
      const int m = m0 + pass * 3 + slot0;
      if (emit_active && m <= mlast) {
        const float th = fmaf((float)m, K255, kneg);
        const float va = fmaf(fmaf(fmaf(c3a, th, c2a), th, fadt), th, za);
        const float vb = fmaf(fmaf(fmaf(c3b, th, c2b), th, fbdt), th, zb);
        pbase[(size_t)m * pstride] = fmaf(va, ca, fmaf(vb, cb, cc));
      }
    }

    za = zna; zb = znb; fa = fna; fb = fnb;
  }
}

extern "C" void kernel_launch(void* const* d_in, const int* in_sizes, int n_in,
                              void* d_out, int out_size, void* d_ws, size_t ws_size,
                              hipStream_t stream)
{
  const float* x   = (const float*)d_in[0];
  const float* We1 = (const float*)d_in[1];
  const float* be1 = (const float*)d_in[2];
  const float* We2 = (const float*)d_in[3];
  const float* be2 = (const float*)d_in[4];
  const float* We3 = (const float*)d_in[5];
  const float* be3 = (const float*)d_in[6];
  const float* Wo1 = (const float*)d_in[7];
  const float* bo1 = (const float*)d_in[8];
  const float* Wo2 = (const float*)d_in[9];
  const float* bo2 = (const float*)d_in[10];
  const float* Wd  = (const float*)d_in[11];
  const float* bd  = (const float*)d_in[12];

  dim3 grid(BATCH * 16 / 256), block(256);
  gait_kernel<<<grid, block, 0, stream>>>(x, We1, be1, We2, be2, We3, be3,
                                          Wo1, bo1, Wo2, bo2, Wd, bd,
                                          (float*)d_out);
}

// Round 7
// 51.588 us; speedup vs baseline: 3.9905x; 1.1447x over previous
//
#include <hip/hip_runtime.h>

// GaitPINN: encoder MLP -> 2-D neural ODE (tanh MLP vector field) -> decoder.
// Fixed-step RK4 + power-basis cubic Hermite dense output replaces dopri5.
// R7: NSEG 32->20 (vf evals 129->81). Error: absmax was bit-identical 0.015625
// across NSEG=85/51/32 (49x truncation swing) -> reference-deviation dominated;
// truncation@32 <~ few e-3, x6.6 at NSEG=20 -> ~0.03 worst case << 0.079.
// Micro: 64-bit emit-address mul -> 32-bit shifts (pstride is 2^15 or 3*2^14);
// bo2 bias folded into lane-0 accumulator init (saves 2 adds/vf; xor-butterfly
// keeps all lanes bitwise identical); emit is a runtime-bounded 3-stride loop.
// Keeps pinned codegen: #pragma unroll 1 main loop (R3: compiler unroll blew
// VGPR 52->156), interchanged encoder, 16 lanes/sample, full-DPP allred16.

constexpr int   BATCH = 16384;
constexpr int   NSEG  = 20;
constexpr float DT    = 1.0f / (float)NSEG;
constexpr float DT2   = DT * 0.5f;
constexpr float DT6   = DT / 6.0f;
constexpr float SCALE = 2.8853900817779268f; // 2*log2(e): tanh(s)=1-2/(1+exp2(SCALE*s))
constexpr float K255  = (float)NSEG / 255.0f; // theta = m*K255 - k

__device__ __forceinline__ float fast_exp2(float x) {
#if __has_builtin(__builtin_amdgcn_exp2f)
  return __builtin_amdgcn_exp2f(x);
#else
  return exp2f(x);
#endif
}

__device__ __forceinline__ float fast_rcp(float x) {
#if __has_builtin(__builtin_amdgcn_rcpf)
  return __builtin_amdgcn_rcpf(x);
#else
  return 1.0f / x;
#endif
}

// v += lane-permuted v, permutation given by DPP ctrl. Full-rate VALU.
template<int CTRL>
__device__ __forceinline__ float dpp_add(float v) {
  int sw = __builtin_amdgcn_update_dpp(0, __float_as_int(v), CTRL, 0xF, 0xF, true);
  return v + __int_as_float(sw);
}

// Butterfly allreduce over each aligned 16-lane group, all full-rate DPP:
// xor1 (quad_perm 0xB1), xor2 (quad_perm 0x4E), row_half_mirror (0x141),
// row_mirror (0x140). Every level adds a commutative pair on both partners ->
// all 16 lanes end bitwise identical (verified R2-R6).
__device__ __forceinline__ float allred16(float v) {
  v = dpp_add<0xB1>(v);
  v = dpp_add<0x4E>(v);
  v = dpp_add<0x141>(v);
  v = dpp_add<0x140>(v);
  return v;
}

__global__ __launch_bounds__(256) void gait_kernel(
    const float* __restrict__ x,
    const float* __restrict__ We1, const float* __restrict__ be1,
    const float* __restrict__ We2, const float* __restrict__ be2,
    const float* __restrict__ We3, const float* __restrict__ be3,
    const float* __restrict__ Wo1, const float* __restrict__ bo1,
    const float* __restrict__ Wo2, const float* __restrict__ bo2,
    const float* __restrict__ Wd,  const float* __restrict__ bd,
    float* __restrict__ out)
{
  const int t   = blockIdx.x * 256 + threadIdx.x;
  const int b   = t >> 4;   // sample id
  const int sub = t & 15;   // lane within the sample's 16-lane group

  // ---------------- encoder, loop-interchanged (R4) ----------------
  const float* xb = x + (size_t)b * 2304;  // x[b, 0, :], row stride 256*9
  float xv[9];
#pragma unroll
  for (int i = 0; i < 9; ++i) xv[i] = xb[i];

  const int c0 = sub * 4;
  float s0 = be2[c0+0], s1 = be2[c0+1], s2 = be2[c0+2], s3 = be2[c0+3];
#pragma unroll 4
  for (int i = 0; i < 64; ++i) {
    float h = be1[i];
#pragma unroll
    for (int j = 0; j < 9; ++j) h = fmaf(xv[j], We1[j*64 + i], h);
    h = fmaxf(h, 0.0f);
    const float* w2r = We2 + i*64 + c0;
    s0 = fmaf(h, w2r[0], s0);
    s1 = fmaf(h, w2r[1], s1);
    s2 = fmaf(h, w2r[2], s2);
    s3 = fmaf(h, w2r[3], s3);
  }
  s0 = fmaxf(s0, 0.0f); s1 = fmaxf(s1, 0.0f);
  s2 = fmaxf(s2, 0.0f); s3 = fmaxf(s3, 0.0f);
  float z0a = fmaf(s0, We3[(c0+0)*2+0], fmaf(s1, We3[(c0+1)*2+0],
              fmaf(s2, We3[(c0+2)*2+0],      s3 * We3[(c0+3)*2+0])));
  float z0b = fmaf(s0, We3[(c0+0)*2+1], fmaf(s1, We3[(c0+1)*2+1],
              fmaf(s2, We3[(c0+2)*2+1],      s3 * We3[(c0+3)*2+1])));
  z0a = allred16(z0a) + be3[0];
  z0b = allred16(z0b) + be3[1];

  // write z0 (out[0 .. 32767]); one lane per sample owns it
  if (sub == 5) {
    float2 v; v.x = z0a; v.y = z0b;
    *reinterpret_cast<float2*>(out + (size_t)b * 2) = v;
  }

  float* __restrict__ zt = out + 32768;             // z_traj (256,16384,2)
  float* __restrict__ xh = out + 32768 + 8388608;   // x_hat  (256,16384,3)

  // ---- spread emit setup: role r = sub%5 picks the output scalar
  // (zt.a, zt.b, xh.0, xh.1, xh.2); slot0 = sub/5 picks the time sub-slot.
  // Lane 15 is parked (huge start slot). val = ca*va + cb*vb + cc.
  // Element offset fits 32 bits; pstride is 2^15 (zt) or 3*2^14 (xh) -> shifts.
  const int r     = sub % 5;
  const int slot0 = (sub < 15) ? (sub / 5) : (1 << 20);
  float ca = 0.f, cb = 0.f, cc = 0.f;
  if      (r == 0) { ca = 1.f; }
  else if (r == 1) { cb = 1.f; }
  else if (r == 2) { ca = Wd[0]; cb = Wd[3]; cc = bd[0]; }
  else if (r == 3) { ca = Wd[1]; cb = Wd[4]; cc = bd[1]; }
  else             { ca = Wd[2]; cb = Wd[5]; cc = bd[2]; }
  float* pbase = (r < 2) ? (zt + (size_t)b * 2 + r)
                         : (xh + (size_t)b * 3 + (r - 2));
  const bool zrole = (r < 2);

  // m = 0 output (theta=0 of segment 0): roles 0..4 live on lanes 0..4
  if (sub < 5) pbase[0] = fmaf(z0a, ca, fmaf(z0b, cb, cc));

  // this lane's 2-wide slice of the 32 hidden units of the vector field
  float w1a[2], w1b[2], b1s[2], w2a[2], w2b[2];
  const int u0 = sub * 2;
#pragma unroll
  for (int q = 0; q < 2; ++q) {
    w1a[q] = Wo1[      u0 + q] * SCALE;   // Wo1[0][u]
    w1b[q] = Wo1[32 +  u0 + q] * SCALE;   // Wo1[1][u]
    b1s[q] = bo1[      u0 + q] * SCALE;
    w2a[q] = Wo2[(u0 + q)*2 + 0];
    w2b[q] = Wo2[(u0 + q)*2 + 1];
  }
  // bo2 folded into lane 0's accumulator init (xor-butterfly keeps all lanes
  // bitwise identical regardless of which lane carries the bias).
  const float a0i = (sub == 0) ? bo2[0] : 0.0f;
  const float a1i = (sub == 0) ? bo2[1] : 0.0f;

  // vf(z) = tanh(z@Wo1+bo1)@Wo2+bo2, split over 16 lanes, DPP-allreduced.
  auto vf = [&](float za, float zb, float& o0, float& o1) {
    float a0 = a0i, a1 = a1i;
#pragma unroll
    for (int q = 0; q < 2; ++q) {
      float u  = fmaf(za, w1a[q], fmaf(zb, w1b[q], b1s[q]));
      float e  = fast_exp2(u);
      float rr = fast_rcp(e + 1.0f);
      float th = fmaf(-2.0f, rr, 1.0f);     // tanh
      a0 = fmaf(th, w2a[q], a0);
      a1 = fmaf(th, w2b[q], a1);
    }
    o0 = allred16(a0);
    o1 = allred16(a1);
  };

  float za = z0a, zb = z0b;
  float fa, fb;
  vf(za, zb, fa, fb);        // k1 of first segment (carried across segments)

  // #pragma unroll 1: R3 lesson — compiler unroll of this loop exploded
  // VGPRs (52->156) and thrashed L1I.
#pragma unroll 1
  for (int k = 0; k < NSEG; ++k) {
    float k2a, k2b, k3a, k3b, k4a, k4b, fna, fnb;
    vf(fmaf(DT2, fa,  za), fmaf(DT2, fb,  zb), k2a, k2b);
    vf(fmaf(DT2, k2a, za), fmaf(DT2, k2b, zb), k3a, k3b);
    vf(fmaf(DT,  k3a, za), fmaf(DT,  k3b, zb), k4a, k4b);
    float zna = fmaf(DT6, fa + k4a + 2.0f*(k2a + k3a), za);
    float znb = fmaf(DT6, fb + k4b + 2.0f*(k2b + k3b), zb);
    vf(zna, znb, fna, fnb);  // next segment's k1 + Hermite end-tangent

    // Dense output: cubic Hermite in power basis, p(th)=((c3*th+c2)*th+c1)*th+c0
    // with c0=z, c1=dt*f, c2=3d-2c1-dt*fn, c3=-2d+c1+dt*fn, d=zn-z.
    const float fadt  = DT * fa,  fbdt  = DT * fb;
    const float fnadt = DT * fna, fnbdt = DT * fnb;
    const float da = zna - za,    db = znb - zb;
    const float c2a = fmaf(3.f, da, -fmaf(2.f, fadt, fnadt));
    const float c3a = fmaf(-2.f, da, fadt + fnadt);
    const float c2b = fmaf(3.f, db, -fmaf(2.f, fbdt, fnbdt));
    const float c3b = fmaf(-2.f, db, fbdt + fnbdt);

    // outputs m with t_m = m/255 in (k/NSEG, (k+1)/NSEG]; 12 or 13 per segment
    const int m0    = (255 * k) / NSEG + 1;
    const int mlast = (255 * (k + 1)) / NSEG;
    const float kneg = -(float)k;
#pragma unroll 1
    for (int m = m0 + slot0; m <= mlast; m += 3) {
      const float th = fmaf((float)m, K255, kneg);
      const float va = fmaf(fmaf(fmaf(c3a, th, c2a), th, fadt), th, za);
      const float vb = fmaf(fmaf(fmaf(c3b, th, c2b), th, fbdt), th, zb);
      const uint32_t off = zrole ? ((uint32_t)m << 15)
                                 : (((uint32_t)m * 3u) << 14);
      pbase[off] = fmaf(va, ca, fmaf(vb, cb, cc));
    }

    za = zna; zb = znb; fa = fna; fb = fnb;
  }
}

extern "C" void kernel_launch(void* const* d_in, const int* in_sizes, int n_in,
                              void* d_out, int out_size, void* d_ws, size_t ws_size,
                              hipStream_t stream)
{
  const float* x   = (const float*)d_in[0];
  const float* We1 = (const float*)d_in[1];
  const float* be1 = (const float*)d_in[2];
  const float* We2 = (const float*)d_in[3];
  const float* be2 = (const float*)d_in[4];
  const float* We3 = (const float*)d_in[5];
  const float* be3 = (const float*)d_in[6];
  const float* Wo1 = (const float*)d_in[7];
  const float* bo1 = (const float*)d_in[8];
  const float* Wo2 = (const float*)d_in[9];
  const float* bo2 = (const float*)d_in[10];
  const float* Wd  = (const float*)d_in[11];
  const float* bd  = (const float*)d_in[12];

  dim3 grid(BATCH * 16 / 256), block(256);
  gait_kernel<<<grid, block, 0, stream>>>(x, We1, be1, We2, be2, We3, be3,
                                          Wo1, bo1, Wo2, bo2, Wd, bd,
                                          (float*)d_out);
}

// Round 8
// 47.612 us; speedup vs baseline: 4.3237x; 1.0835x over previous
//
#include <hip/hip_runtime.h>

// GaitPINN: encoder MLP -> 2-D neural ODE (tanh MLP vector field) -> decoder.
// Fixed-step RK4 + power-basis cubic Hermite dense output replaces dopri5.
// R8: (a) NSEG 20->16 (vf evals 81->65). Empirical error bound: absmax was
//     bit-identical 0.015625 across NSEG=85/51/32/20 -> truncation@20 < 0.0156
//     everywhere; x(20/16)^4=2.44 -> truncation@16 < 0.038; worst-case total
//     0.054 < 0.079 threshold.
//     (b) combined-cubic emit: fold per-lane decoder coeffs (ca,cb,cc) into
//     the Hermite cubic once per segment (C0..C3), so each output is one
//     3-FMA Horner + incremental th instead of two cubics + combine.
// Keeps pinned codegen: #pragma unroll 1 main loop (R3: compiler unroll blew
// VGPR 52->156), interchanged encoder, 16 lanes/sample, full-DPP allred16,
// bo2 folded into lane-0 accumulator init.

constexpr int   BATCH = 16384;
constexpr int   NSEG  = 16;
constexpr float DT    = 1.0f / (float)NSEG;
constexpr float DT2   = DT * 0.5f;
constexpr float DT6   = DT / 6.0f;
constexpr float SCALE = 2.8853900817779268f; // 2*log2(e): tanh(s)=1-2/(1+exp2(SCALE*s))
constexpr float K255  = (float)NSEG / 255.0f; // theta = m*K255 - k
constexpr float TH3   = 3.0f * K255;          // per-iteration theta step

__device__ __forceinline__ float fast_exp2(float x) {
#if __has_builtin(__builtin_amdgcn_exp2f)
  return __builtin_amdgcn_exp2f(x);
#else
  return exp2f(x);
#endif
}

__device__ __forceinline__ float fast_rcp(float x) {
#if __has_builtin(__builtin_amdgcn_rcpf)
  return __builtin_amdgcn_rcpf(x);
#else
  return 1.0f / x;
#endif
}

// v += lane-permuted v, permutation given by DPP ctrl. Full-rate VALU.
template<int CTRL>
__device__ __forceinline__ float dpp_add(float v) {
  int sw = __builtin_amdgcn_update_dpp(0, __float_as_int(v), CTRL, 0xF, 0xF, true);
  return v + __int_as_float(sw);
}

// Butterfly allreduce over each aligned 16-lane group, all full-rate DPP:
// xor1 (quad_perm 0xB1), xor2 (quad_perm 0x4E), row_half_mirror (0x141),
// row_mirror (0x140). Every level adds the same commutative pair on both
// partners -> all 16 lanes end bitwise identical (verified R2-R7).
__device__ __forceinline__ float allred16(float v) {
  v = dpp_add<0xB1>(v);
  v = dpp_add<0x4E>(v);
  v = dpp_add<0x141>(v);
  v = dpp_add<0x140>(v);
  return v;
}

__global__ __launch_bounds__(256) void gait_kernel(
    const float* __restrict__ x,
    const float* __restrict__ We1, const float* __restrict__ be1,
    const float* __restrict__ We2, const float* __restrict__ be2,
    const float* __restrict__ We3, const float* __restrict__ be3,
    const float* __restrict__ Wo1, const float* __restrict__ bo1,
    const float* __restrict__ Wo2, const float* __restrict__ bo2,
    const float* __restrict__ Wd,  const float* __restrict__ bd,
    float* __restrict__ out)
{
  const int t   = blockIdx.x * 256 + threadIdx.x;
  const int b   = t >> 4;   // sample id
  const int sub = t & 15;   // lane within the sample's 16-lane group

  // ---------------- encoder, loop-interchanged (R4) ----------------
  const float* xb = x + (size_t)b * 2304;  // x[b, 0, :], row stride 256*9
  float xv[9];
#pragma unroll
  for (int i = 0; i < 9; ++i) xv[i] = xb[i];

  const int c0 = sub * 4;
  float s0 = be2[c0+0], s1 = be2[c0+1], s2 = be2[c0+2], s3 = be2[c0+3];
#pragma unroll 4
  for (int i = 0; i < 64; ++i) {
    float h = be1[i];
#pragma unroll
    for (int j = 0; j < 9; ++j) h = fmaf(xv[j], We1[j*64 + i], h);
    h = fmaxf(h, 0.0f);
    const float* w2r = We2 + i*64 + c0;
    s0 = fmaf(h, w2r[0], s0);
    s1 = fmaf(h, w2r[1], s1);
    s2 = fmaf(h, w2r[2], s2);
    s3 = fmaf(h, w2r[3], s3);
  }
  s0 = fmaxf(s0, 0.0f); s1 = fmaxf(s1, 0.0f);
  s2 = fmaxf(s2, 0.0f); s3 = fmaxf(s3, 0.0f);
  float z0a = fmaf(s0, We3[(c0+0)*2+0], fmaf(s1, We3[(c0+1)*2+0],
              fmaf(s2, We3[(c0+2)*2+0],      s3 * We3[(c0+3)*2+0])));
  float z0b = fmaf(s0, We3[(c0+0)*2+1], fmaf(s1, We3[(c0+1)*2+1],
              fmaf(s2, We3[(c0+2)*2+1],      s3 * We3[(c0+3)*2+1])));
  z0a = allred16(z0a) + be3[0];
  z0b = allred16(z0b) + be3[1];

  // write z0 (out[0 .. 32767]); one lane per sample owns it
  if (sub == 5) {
    float2 v; v.x = z0a; v.y = z0b;
    *reinterpret_cast<float2*>(out + (size_t)b * 2) = v;
  }

  float* __restrict__ zt = out + 32768;             // z_traj (256,16384,2)
  float* __restrict__ xh = out + 32768 + 8388608;   // x_hat  (256,16384,3)

  // ---- spread emit setup: role r = sub%5 picks the output scalar
  // (zt.a, zt.b, xh.0, xh.1, xh.2); slot0 = sub/5 picks the time sub-slot
  // (stride 3). Lane 15 is parked via a huge start slot.
  const int r     = sub % 5;
  const int slot0 = (sub < 15) ? (sub / 5) : (1 << 20);
  float ca = 0.f, cb = 0.f, cc = 0.f;
  if      (r == 0) { ca = 1.f; }
  else if (r == 1) { cb = 1.f; }
  else if (r == 2) { ca = Wd[0]; cb = Wd[3]; cc = bd[0]; }
  else if (r == 3) { ca = Wd[1]; cb = Wd[4]; cc = bd[1]; }
  else             { ca = Wd[2]; cb = Wd[5]; cc = bd[2]; }
  float* pbase = (r < 2) ? (zt + (size_t)b * 2 + r)
                         : (xh + (size_t)b * 3 + (r - 2));
  const uint32_t pstride = (r < 2) ? 32768u : 49152u;  // elems per time index
  const uint32_t pstride3 = 3u * pstride;

  // m = 0 output (theta=0 of segment 0): roles 0..4 live on lanes 0..4
  if (sub < 5) pbase[0] = fmaf(z0a, ca, fmaf(z0b, cb, cc));

  // this lane's 2-wide slice of the 32 hidden units of the vector field
  float w1a[2], w1b[2], b1s[2], w2a[2], w2b[2];
  const int u0 = sub * 2;
#pragma unroll
  for (int q = 0; q < 2; ++q) {
    w1a[q] = Wo1[      u0 + q] * SCALE;   // Wo1[0][u]
    w1b[q] = Wo1[32 +  u0 + q] * SCALE;   // Wo1[1][u]
    b1s[q] = bo1[      u0 + q] * SCALE;
    w2a[q] = Wo2[(u0 + q)*2 + 0];
    w2b[q] = Wo2[(u0 + q)*2 + 1];
  }
  // bo2 folded into lane 0's accumulator init (xor-butterfly keeps all lanes
  // bitwise identical regardless of which lane carries the bias).
  const float a0i = (sub == 0) ? bo2[0] : 0.0f;
  const float a1i = (sub == 0) ? bo2[1] : 0.0f;

  // vf(z) = tanh(z@Wo1+bo1)@Wo2+bo2, split over 16 lanes, DPP-allreduced.
  auto vf = [&](float za, float zb, float& o0, float& o1) {
    float a0 = a0i, a1 = a1i;
#pragma unroll
    for (int q = 0; q < 2; ++q) {
      float u  = fmaf(za, w1a[q], fmaf(zb, w1b[q], b1s[q]));
      float e  = fast_exp2(u);
      float rr = fast_rcp(e + 1.0f);
      float th = fmaf(-2.0f, rr, 1.0f);     // tanh
      a0 = fmaf(th, w2a[q], a0);
      a1 = fmaf(th, w2b[q], a1);
    }
    o0 = allred16(a0);
    o1 = allred16(a1);
  };

  float za = z0a, zb = z0b;
  float fa, fb;
  vf(za, zb, fa, fb);        // k1 of first segment (carried across segments)

  // #pragma unroll 1: R3 lesson — compiler unroll of this loop exploded
  // VGPRs (52->156) and thrashed L1I.
#pragma unroll 1
  for (int k = 0; k < NSEG; ++k) {
    float k2a, k2b, k3a, k3b, k4a, k4b, fna, fnb;
    vf(fmaf(DT2, fa,  za), fmaf(DT2, fb,  zb), k2a, k2b);
    vf(fmaf(DT2, k2a, za), fmaf(DT2, k2b, zb), k3a, k3b);
    vf(fmaf(DT,  k3a, za), fmaf(DT,  k3b, zb), k4a, k4b);
    float zna = fmaf(DT6, fa + k4a + 2.0f*(k2a + k3a), za);
    float znb = fmaf(DT6, fb + k4b + 2.0f*(k2b + k3b), zb);
    vf(zna, znb, fna, fnb);  // next segment's k1 + Hermite end-tangent

    // Combined-cubic dense output: fold this lane's (ca,cb,cc) into the
    // Hermite cubic once per segment. val(th) = ((C3*th+C2)*th+C1)*th+C0 with
    //   D  = ca*(zn-z) + cb*(zn-z)_b,  C1 = DT*(ca*fa+cb*fb),
    //   Fn = DT*(ca*fna+cb*fnb),       C2 = 3D-2C1-Fn,  C3 = -2D+C1+Fn,
    //   C0 = ca*z + cb*z_b + cc.
    const float da_ = zna - za, db_ = znb - zb;
    const float D  = fmaf(ca, da_, cb * db_);
    const float C1 = DT * fmaf(ca, fa,  cb * fb);
    const float Fn = DT * fmaf(ca, fna, cb * fnb);
    const float C2 = fmaf(3.f, D, -fmaf(2.f, C1, Fn));
    const float C3 = fmaf(-2.f, D, C1 + Fn);
    const float C0 = fmaf(ca, za, fmaf(cb, zb, cc));

    // outputs m with t_m = m/255 in (k/16, (k+1)/16]; 15 or 16 per segment
    const int m0    = ((255 * k) >> 4) + 1;
    const int mlast = (255 * (k + 1)) >> 4;
    int m = m0 + slot0;
    float th = fmaf((float)m, K255, -(float)k);
    uint32_t off = (uint32_t)m * pstride;
#pragma unroll 1
    for (; m <= mlast; m += 3) {
      pbase[off] = fmaf(fmaf(fmaf(C3, th, C2), th, C1), th, C0);
      th  += TH3;
      off += pstride3;
    }

    za = zna; zb = znb; fa = fna; fb = fnb;
  }
}

extern "C" void kernel_launch(void* const* d_in, const int* in_sizes, int n_in,
                              void* d_out, int out_size, void* d_ws, size_t ws_size,
                              hipStream_t stream)
{
  const float* x   = (const float*)d_in[0];
  const float* We1 = (const float*)d_in[1];
  const float* be1 = (const float*)d_in[2];
  const float* We2 = (const float*)d_in[3];
  const float* be2 = (const float*)d_in[4];
  const float* We3 = (const float*)d_in[5];
  const float* be3 = (const float*)d_in[6];
  const float* Wo1 = (const float*)d_in[7];
  const float* bo1 = (const float*)d_in[8];
  const float* Wo2 = (const float*)d_in[9];
  const float* bo2 = (const float*)d_in[10];
  const float* Wd  = (const float*)d_in[11];
  const float* bd  = (const float*)d_in[12];

  dim3 grid(BATCH * 16 / 256), block(256);
  gait_kernel<<<grid, block, 0, stream>>>(x, We1, be1, We2, be2, We3, be3,
                                          Wo1, bo1, Wo2, bo2, Wd, bd,
                                          (float*)d_out);
}

// Round 9
// 46.438 us; speedup vs baseline: 4.4330x; 1.0253x over previous
//
#include <hip/hip_runtime.h>

// GaitPINN: encoder MLP -> 2-D neural ODE (tanh MLP vector field) -> decoder.
// Fixed-step RK4 + power-basis cubic Hermite dense output replaces dopri5.
// R9: (a) NSEG 16->12 (vf evals 65->49). Empirical error: absmax bit-identical
//     0.015625 across NSEG=85/51/32/20/16 (800x dt^4 swing) -> truncation@16
//     <~2e-3; x3.16 at NSEG=12 -> <~6e-3 added, total << 0.079.
//     (b) software-pipelined emit: segment k-1's combined-cubic outputs are
//     emitted in two 4-slot chunks interleaved BETWEEN segment k's vf calls,
//     filling the serial vf-chain latency bubbles (B~31us fixed cost in the
//     dur = 0.25us*evals + B fit across R4-R8). Emit guards use exact integer
//     m compares (never float th) so no output is skipped by rounding.
// Keeps pinned codegen: #pragma unroll 1 main loop (R3: compiler unroll blew
// VGPR 52->156), interchanged encoder, 16 lanes/sample, full-DPP allred16,
// bo2 folded into lane-0 accumulator init.

constexpr int   BATCH = 16384;
constexpr int   NSEG  = 12;
constexpr float DT    = 1.0f / (float)NSEG;
constexpr float DT2   = DT * 0.5f;
constexpr float DT6   = DT / 6.0f;
constexpr float SCALE = 2.8853900817779268f; // 2*log2(e): tanh(s)=1-2/(1+exp2(SCALE*s))
constexpr float K255  = (float)NSEG / 255.0f; // theta = m*K255 - k

__device__ __forceinline__ float fast_exp2(float x) {
#if __has_builtin(__builtin_amdgcn_exp2f)
  return __builtin_amdgcn_exp2f(x);
#else
  return exp2f(x);
#endif
}

__device__ __forceinline__ float fast_rcp(float x) {
#if __has_builtin(__builtin_amdgcn_rcpf)
  return __builtin_amdgcn_rcpf(x);
#else
  return 1.0f / x;
#endif
}

// v += lane-permuted v, permutation given by DPP ctrl. Full-rate VALU.
template<int CTRL>
__device__ __forceinline__ float dpp_add(float v) {
  int sw = __builtin_amdgcn_update_dpp(0, __float_as_int(v), CTRL, 0xF, 0xF, true);
  return v + __int_as_float(sw);
}

// Butterfly allreduce over each aligned 16-lane group, all full-rate DPP:
// xor1 (quad_perm 0xB1), xor2 (quad_perm 0x4E), row_half_mirror (0x141),
// row_mirror (0x140). Every level adds the same commutative pair on both
// partners -> all 16 lanes end bitwise identical (verified R2-R8).
__device__ __forceinline__ float allred16(float v) {
  v = dpp_add<0xB1>(v);
  v = dpp_add<0x4E>(v);
  v = dpp_add<0x141>(v);
  v = dpp_add<0x140>(v);
  return v;
}

__global__ __launch_bounds__(256) void gait_kernel(
    const float* __restrict__ x,
    const float* __restrict__ We1, const float* __restrict__ be1,
    const float* __restrict__ We2, const float* __restrict__ be2,
    const float* __restrict__ We3, const float* __restrict__ be3,
    const float* __restrict__ Wo1, const float* __restrict__ bo1,
    const float* __restrict__ Wo2, const float* __restrict__ bo2,
    const float* __restrict__ Wd,  const float* __restrict__ bd,
    float* __restrict__ out)
{
  const int t   = blockIdx.x * 256 + threadIdx.x;
  const int b   = t >> 4;   // sample id
  const int sub = t & 15;   // lane within the sample's 16-lane group

  // ---------------- encoder, loop-interchanged (R4) ----------------
  const float* xb = x + (size_t)b * 2304;  // x[b, 0, :], row stride 256*9
  float xv[9];
#pragma unroll
  for (int i = 0; i < 9; ++i) xv[i] = xb[i];

  const int c0 = sub * 4;
  float s0 = be2[c0+0], s1 = be2[c0+1], s2 = be2[c0+2], s3 = be2[c0+3];
#pragma unroll 4
  for (int i = 0; i < 64; ++i) {
    float h = be1[i];
#pragma unroll
    for (int j = 0; j < 9; ++j) h = fmaf(xv[j], We1[j*64 + i], h);
    h = fmaxf(h, 0.0f);
    const float* w2r = We2 + i*64 + c0;
    s0 = fmaf(h, w2r[0], s0);
    s1 = fmaf(h, w2r[1], s1);
    s2 = fmaf(h, w2r[2], s2);
    s3 = fmaf(h, w2r[3], s3);
  }
  s0 = fmaxf(s0, 0.0f); s1 = fmaxf(s1, 0.0f);
  s2 = fmaxf(s2, 0.0f); s3 = fmaxf(s3, 0.0f);
  float z0a = fmaf(s0, We3[(c0+0)*2+0], fmaf(s1, We3[(c0+1)*2+0],
              fmaf(s2, We3[(c0+2)*2+0],      s3 * We3[(c0+3)*2+0])));
  float z0b = fmaf(s0, We3[(c0+0)*2+1], fmaf(s1, We3[(c0+1)*2+1],
              fmaf(s2, We3[(c0+2)*2+1],      s3 * We3[(c0+3)*2+1])));
  z0a = allred16(z0a) + be3[0];
  z0b = allred16(z0b) + be3[1];

  // write z0 (out[0 .. 32767]); one lane per sample owns it
  if (sub == 5) {
    float2 v; v.x = z0a; v.y = z0b;
    *reinterpret_cast<float2*>(out + (size_t)b * 2) = v;
  }

  float* __restrict__ zt = out + 32768;             // z_traj (256,16384,2)
  float* __restrict__ xh = out + 32768 + 8388608;   // x_hat  (256,16384,3)

  // ---- spread emit setup: role r = sub%5 picks the output scalar
  // (zt.a, zt.b, xh.0, xh.1, xh.2); slot0 = sub/5 picks the time sub-slot
  // (stride 3). Lane 15 is parked via a huge slot (int m compare fails).
  const int r     = sub % 5;
  const int slot0 = (sub < 15) ? (sub / 5) : (1 << 20);
  float ca = 0.f, cb = 0.f, cc = 0.f;
  if      (r == 0) { ca = 1.f; }
  else if (r == 1) { cb = 1.f; }
  else if (r == 2) { ca = Wd[0]; cb = Wd[3]; cc = bd[0]; }
  else if (r == 3) { ca = Wd[1]; cb = Wd[4]; cc = bd[1]; }
  else             { ca = Wd[2]; cb = Wd[5]; cc = bd[2]; }
  float* pbase = (r < 2) ? (zt + (size_t)b * 2 + r)
                         : (xh + (size_t)b * 3 + (r - 2));
  const uint32_t pstride  = (r < 2) ? 32768u : 49152u; // elems per time index
  const uint32_t pstride3 = 3u * pstride;

  // m = 0 output (theta=0 of segment 0): roles 0..4 live on lanes 0..4
  if (sub < 5) pbase[0] = fmaf(z0a, ca, fmaf(z0b, cb, cc));

  // this lane's 2-wide slice of the 32 hidden units of the vector field
  float w1a[2], w1b[2], b1s[2], w2a[2], w2b[2];
  const int u0 = sub * 2;
#pragma unroll
  for (int q = 0; q < 2; ++q) {
    w1a[q] = Wo1[      u0 + q] * SCALE;   // Wo1[0][u]
    w1b[q] = Wo1[32 +  u0 + q] * SCALE;   // Wo1[1][u]
    b1s[q] = bo1[      u0 + q] * SCALE;
    w2a[q] = Wo2[(u0 + q)*2 + 0];
    w2b[q] = Wo2[(u0 + q)*2 + 1];
  }
  // bo2 folded into lane 0's accumulator init (xor-butterfly keeps all lanes
  // bitwise identical regardless of which lane carries the bias).
  const float a0i = (sub == 0) ? bo2[0] : 0.0f;
  const float a1i = (sub == 0) ? bo2[1] : 0.0f;

  // vf(z) = tanh(z@Wo1+bo1)@Wo2+bo2, split over 16 lanes, DPP-allreduced.
  auto vf = [&](float za, float zb, float& o0, float& o1) {
    float a0 = a0i, a1 = a1i;
#pragma unroll
    for (int q = 0; q < 2; ++q) {
      float u  = fmaf(za, w1a[q], fmaf(zb, w1b[q], b1s[q]));
      float e  = fast_exp2(u);
      float rr = fast_rcp(e + 1.0f);
      float th = fmaf(-2.0f, rr, 1.0f);     // tanh
      a0 = fmaf(th, w2a[q], a0);
      a1 = fmaf(th, w2b[q], a1);
    }
    o0 = allred16(a0);
    o1 = allred16(a1);
  };

  // ---- software-pipelined emit state (previous segment's combined cubic) ----
  // val(th) = ((pC3*th+pC2)*th+pC1)*th+pC0, th = m*K255 - k_prev.
  float pC0 = 0.f, pC1 = 0.f, pC2 = 0.f, pC3 = 0.f, pkneg = 0.f;
  int   pim0 = 0, pml = -1;      // empty range -> k=0's chunks are masked
  uint32_t poff = 0;

  // emit 4 slots (jb..jb+3) of the carried segment; int-m guard is exact.
  auto emit4 = [&](int jb) {
#pragma unroll
    for (int j = 0; j < 4; ++j) {
      const int im = pim0 + 3 * (jb + j);
      if (im <= pml) {
        const float th = fmaf((float)im, K255, pkneg);
        pbase[poff + (uint32_t)(jb + j) * pstride3] =
            fmaf(fmaf(fmaf(pC3, th, pC2), th, pC1), th, pC0);
      }
    }
  };

  float za = z0a, zb = z0b;
  float fa, fb;
  vf(za, zb, fa, fb);        // k1 of first segment (carried across segments)

  // #pragma unroll 1: R3 lesson — compiler unroll of this loop exploded
  // VGPRs (52->156) and thrashed L1I.
#pragma unroll 1
  for (int k = 0; k < NSEG; ++k) {
    float k2a, k2b, k3a, k3b, k4a, k4b, fna, fnb;
    vf(fmaf(DT2, fa,  za), fmaf(DT2, fb,  zb), k2a, k2b);
    emit4(0);                // prev segment outputs, slots 0-3 (fills bubbles)
    vf(fmaf(DT2, k2a, za), fmaf(DT2, k2b, zb), k3a, k3b);
    emit4(4);                // prev segment outputs, slots 4-7
    vf(fmaf(DT,  k3a, za), fmaf(DT,  k3b, zb), k4a, k4b);
    float zna = fmaf(DT6, fa + k4a + 2.0f*(k2a + k3a), za);
    float znb = fmaf(DT6, fb + k4b + 2.0f*(k2b + k3b), zb);
    vf(zna, znb, fna, fnb);  // next segment's k1 + Hermite end-tangent

    // Combined cubic for THIS segment (emitted during the next iteration):
    //   D  = ca*(zn-z)+cb*(zn-z)_b, C1 = DT*(ca*fa+cb*fb),
    //   Fn = DT*(ca*fna+cb*fnb),    C2 = 3D-2C1-Fn, C3 = -2D+C1+Fn,
    //   C0 = ca*z+cb*z_b+cc.
    const float da_ = zna - za, db_ = znb - zb;
    const float D  = fmaf(ca, da_, cb * db_);
    pC1 = DT * fmaf(ca, fa,  cb * fb);
    const float Fn = DT * fmaf(ca, fna, cb * fnb);
    pC2 = fmaf(3.f, D, -fmaf(2.f, pC1, Fn));
    pC3 = fmaf(-2.f, D, pC1 + Fn);
    pC0 = fmaf(ca, za, fmaf(cb, zb, cc));
    const int m0 = (255 * k) / NSEG + 1;      // uniform scalar math
    pml  = (255 * (k + 1)) / NSEG;            // 21 or 22 outputs per segment
    pim0 = m0 + slot0;
    pkneg = -(float)k;
    poff  = (uint32_t)pim0 * pstride;         // masked lanes may wrap: unused

    za = zna; zb = znb; fa = fna; fb = fnb;
  }

  // epilogue: emit the final segment's outputs
  emit4(0);
  emit4(4);
}

extern "C" void kernel_launch(void* const* d_in, const int* in_sizes, int n_in,
                              void* d_out, int out_size, void* d_ws, size_t ws_size,
                              hipStream_t stream)
{
  const float* x   = (const float*)d_in[0];
  const float* We1 = (const float*)d_in[1];
  const float* be1 = (const float*)d_in[2];
  const float* We2 = (const float*)d_in[3];
  const float* be2 = (const float*)d_in[4];
  const float* We3 = (const float*)d_in[5];
  const float* be3 = (const float*)d_in[6];
  const float* Wo1 = (const float*)d_in[7];
  const float* bo1 = (const float*)d_in[8];
  const float* Wo2 = (const float*)d_in[9];
  const float* bo2 = (const float*)d_in[10];
  const float* Wd  = (const float*)d_in[11];
  const float* bd  = (const float*)d_in[12];

  dim3 grid(BATCH * 16 / 256), block(256);
  gait_kernel<<<grid, block, 0, stream>>>(x, We1, be1, We2, be2, We3, be3,
                                          Wo1, bo1, Wo2, bo2, Wd, bd,
                                          (float*)d_out);
}

// Round 10
// 41.362 us; speedup vs baseline: 4.9771x; 1.1227x over previous
//
#include <hip/hip_runtime.h>

// GaitPINN: encoder MLP -> 2-D neural ODE (tanh MLP vector field) -> decoder.
// R10: two-kernel split. Kernel A (gait_integrate): encoder + RK4 (NSEG=12,
// 16 lanes/sample, full-DPP allred16) with ALL emit machinery removed; stores
// 13 boundary states (za,zb,fa,fb) as float4 to d_ws (3.4MB, 64B/wave/boundary
// coalesced). Kernel B (gait_emit): 4.2M threads, one per (time m, sample b);
// wave-uniform segment k, coalesced float4 boundary reads (L2-resident),
// power-basis cubic Hermite + decoder, dense coalesced writes. B is
// write-BW-bound (~84MB); A sheds the fixed emit cost identified in the
// R4-R9 fit (dur = A*evals + ~40us fixed, fixed part ~= emit + latency).
// Fallback: if ws_size is too small, launch the R9 fused kernel.
// Pinned-codegen lessons kept: #pragma unroll 1 on serial loops (R3: compiler
// unroll blew VGPR 52->156), interchanged encoder, bo2 folded into lane 0.

constexpr int   BATCH = 16384;
constexpr int   NSEG  = 12;
constexpr float DT    = 1.0f / (float)NSEG;
constexpr float DT2   = DT * 0.5f;
constexpr float DT6   = DT / 6.0f;
constexpr float SCALE = 2.8853900817779268f; // 2*log2(e): tanh(s)=1-2/(1+exp2(SCALE*s))
constexpr float K255  = (float)NSEG / 255.0f; // theta = m*K255 - k

__device__ __forceinline__ float fast_exp2(float x) {
#if __has_builtin(__builtin_amdgcn_exp2f)
  return __builtin_amdgcn_exp2f(x);
#else
  return exp2f(x);
#endif
}

__device__ __forceinline__ float fast_rcp(float x) {
#if __has_builtin(__builtin_amdgcn_rcpf)
  return __builtin_amdgcn_rcpf(x);
#else
  return 1.0f / x;
#endif
}

// v += lane-permuted v, permutation given by DPP ctrl. Full-rate VALU.
template<int CTRL>
__device__ __forceinline__ float dpp_add(float v) {
  int sw = __builtin_amdgcn_update_dpp(0, __float_as_int(v), CTRL, 0xF, 0xF, true);
  return v + __int_as_float(sw);
}

// Butterfly allreduce over each aligned 16-lane group, all full-rate DPP:
// xor1 (quad_perm 0xB1), xor2 (quad_perm 0x4E), row_half_mirror (0x141),
// row_mirror (0x140). All 16 lanes end bitwise identical (verified R2-R9).
__device__ __forceinline__ float allred16(float v) {
  v = dpp_add<0xB1>(v);
  v = dpp_add<0x4E>(v);
  v = dpp_add<0x141>(v);
  v = dpp_add<0x140>(v);
  return v;
}

// ---------------------------------------------------------------------------
// Kernel A: encoder + RK4 integration; stores boundary (z, f) float4s.
// ---------------------------------------------------------------------------
__global__ __launch_bounds__(256) void gait_integrate(
    const float* __restrict__ x,
    const float* __restrict__ We1, const float* __restrict__ be1,
    const float* __restrict__ We2, const float* __restrict__ be2,
    const float* __restrict__ We3, const float* __restrict__ be3,
    const float* __restrict__ Wo1, const float* __restrict__ bo1,
    const float* __restrict__ Wo2, const float* __restrict__ bo2,
    float* __restrict__ out, float4* __restrict__ bnd)
{
  const int t   = blockIdx.x * 256 + threadIdx.x;
  const int b   = t >> 4;   // sample id
  const int sub = t & 15;   // lane within the sample's 16-lane group

  // ---------------- encoder, loop-interchanged (R4) ----------------
  const float* xb = x + (size_t)b * 2304;  // x[b, 0, :], row stride 256*9
  float xv[9];
#pragma unroll
  for (int i = 0; i < 9; ++i) xv[i] = xb[i];

  const int c0 = sub * 4;
  float s0 = be2[c0+0], s1 = be2[c0+1], s2 = be2[c0+2], s3 = be2[c0+3];
#pragma unroll 4
  for (int i = 0; i < 64; ++i) {
    float h = be1[i];
#pragma unroll
    for (int j = 0; j < 9; ++j) h = fmaf(xv[j], We1[j*64 + i], h);
    h = fmaxf(h, 0.0f);
    const float* w2r = We2 + i*64 + c0;
    s0 = fmaf(h, w2r[0], s0);
    s1 = fmaf(h, w2r[1], s1);
    s2 = fmaf(h, w2r[2], s2);
    s3 = fmaf(h, w2r[3], s3);
  }
  s0 = fmaxf(s0, 0.0f); s1 = fmaxf(s1, 0.0f);
  s2 = fmaxf(s2, 0.0f); s3 = fmaxf(s3, 0.0f);
  float z0a = fmaf(s0, We3[(c0+0)*2+0], fmaf(s1, We3[(c0+1)*2+0],
              fmaf(s2, We3[(c0+2)*2+0],      s3 * We3[(c0+3)*2+0])));
  float z0b = fmaf(s0, We3[(c0+0)*2+1], fmaf(s1, We3[(c0+1)*2+1],
              fmaf(s2, We3[(c0+2)*2+1],      s3 * We3[(c0+3)*2+1])));
  z0a = allred16(z0a) + be3[0];
  z0b = allred16(z0b) + be3[1];

  // write z0 (out[0 .. 32767])
  if (sub == 5) {
    float2 v; v.x = z0a; v.y = z0b;
    *reinterpret_cast<float2*>(out + (size_t)b * 2) = v;
  }

  // this lane's 2-wide slice of the 32 hidden units of the vector field
  float w1a[2], w1b[2], b1s[2], w2a[2], w2b[2];
  const int u0 = sub * 2;
#pragma unroll
  for (int q = 0; q < 2; ++q) {
    w1a[q] = Wo1[      u0 + q] * SCALE;   // Wo1[0][u]
    w1b[q] = Wo1[32 +  u0 + q] * SCALE;   // Wo1[1][u]
    b1s[q] = bo1[      u0 + q] * SCALE;
    w2a[q] = Wo2[(u0 + q)*2 + 0];
    w2b[q] = Wo2[(u0 + q)*2 + 1];
  }
  // bo2 folded into lane 0's accumulator init (xor-butterfly keeps all lanes
  // bitwise identical regardless of which lane carries the bias).
  const float a0i = (sub == 0) ? bo2[0] : 0.0f;
  const float a1i = (sub == 0) ? bo2[1] : 0.0f;

  auto vf = [&](float za, float zb, float& o0, float& o1) {
    float a0 = a0i, a1 = a1i;
#pragma unroll
    for (int q = 0; q < 2; ++q) {
      float u  = fmaf(za, w1a[q], fmaf(zb, w1b[q], b1s[q]));
      float e  = fast_exp2(u);
      float rr = fast_rcp(e + 1.0f);
      float th = fmaf(-2.0f, rr, 1.0f);     // tanh
      a0 = fmaf(th, w2a[q], a0);
      a1 = fmaf(th, w2b[q], a1);
    }
    o0 = allred16(a0);
    o1 = allred16(a1);
  };

  float za = z0a, zb = z0b;
  float fa, fb;
  vf(za, zb, fa, fb);        // k1 of first segment (carried across segments)

  // Boundary store: lane 0 of each group; lanes 0,16,32,48 of a wave write
  // 4 consecutive float4s -> one 64B line per wave per boundary.
  const bool storer = (sub == 0);
  float4* wrow = bnd + b;

  // #pragma unroll 1: R3 lesson — compiler unroll exploded VGPRs (52->156).
#pragma unroll 1
  for (int k = 0; k < NSEG; ++k) {
    if (storer) { float4 v; v.x = za; v.y = zb; v.z = fa; v.w = fb;
                  wrow[k * BATCH] = v; }
    float k2a, k2b, k3a, k3b, k4a, k4b, fna, fnb;
    vf(fmaf(DT2, fa,  za), fmaf(DT2, fb,  zb), k2a, k2b);
    vf(fmaf(DT2, k2a, za), fmaf(DT2, k2b, zb), k3a, k3b);
    vf(fmaf(DT,  k3a, za), fmaf(DT,  k3b, zb), k4a, k4b);
    float zna = fmaf(DT6, fa + k4a + 2.0f*(k2a + k3a), za);
    float znb = fmaf(DT6, fb + k4b + 2.0f*(k2b + k3b), zb);
    vf(zna, znb, fna, fnb);  // next segment's k1 + Hermite end-tangent
    za = zna; zb = znb; fa = fna; fb = fnb;
  }
  if (storer) { float4 v; v.x = za; v.y = zb; v.z = fa; v.w = fb;
                wrow[NSEG * BATCH] = v; }
}

// ---------------------------------------------------------------------------
// Kernel B: dense output. One thread per (time m, sample b).
// ---------------------------------------------------------------------------
__global__ __launch_bounds__(256) void gait_emit(
    const float4* __restrict__ bnd,
    const float* __restrict__ Wd, const float* __restrict__ bd,
    float* __restrict__ out)
{
  const int idx = blockIdx.x * 256 + threadIdx.x;
  const int m   = idx >> 14;          // 0..255, wave-uniform
  const int b   = idx & (BATCH - 1);  // consecutive across the wave

  int k = (m * NSEG) / 255;           // segment; exact integer math
  if (k > NSEG - 1) k = NSEG - 1;     // m=255 -> k=11, th=1
  const float th = fmaf((float)m, K255, -(float)k);

  const float4 p0 = bnd[k * BATCH + b];        // (z_k, f_k)
  const float4 p1 = bnd[(k + 1) * BATCH + b];  // (z_{k+1}, f_{k+1})

  const float fadt  = DT * p0.z, fbdt  = DT * p0.w;
  const float fnadt = DT * p1.z, fnbdt = DT * p1.w;
  const float da = p1.x - p0.x, db = p1.y - p0.y;
  const float c2a = fmaf(3.f, da, -fmaf(2.f, fadt, fnadt));
  const float c3a = fmaf(-2.f, da, fadt + fnadt);
  const float c2b = fmaf(3.f, db, -fmaf(2.f, fbdt, fnbdt));
  const float c3b = fmaf(-2.f, db, fbdt + fnbdt);

  const float va = fmaf(fmaf(fmaf(c3a, th, c2a), th, fadt), th, p0.x);
  const float vb = fmaf(fmaf(fmaf(c3b, th, c2b), th, fbdt), th, p0.y);

  float* __restrict__ zt = out + 32768;
  float* __restrict__ xh = out + 32768 + 8388608;

  float2 zv; zv.x = va; zv.y = vb;
  *reinterpret_cast<float2*>(zt + ((size_t)m << 15) + 2 * b) = zv;

  float* q = xh + (size_t)m * 49152 + 3 * b;
  q[0] = fmaf(va, Wd[0], fmaf(vb, Wd[3], bd[0]));
  q[1] = fmaf(va, Wd[1], fmaf(vb, Wd[4], bd[1]));
  q[2] = fmaf(va, Wd[2], fmaf(vb, Wd[5], bd[2]));
}

// ---------------------------------------------------------------------------
// Fallback fused kernel (R9) — used only if ws_size is too small.
// ---------------------------------------------------------------------------
__global__ __launch_bounds__(256) void gait_fused(
    const float* __restrict__ x,
    const float* __restrict__ We1, const float* __restrict__ be1,
    const float* __restrict__ We2, const float* __restrict__ be2,
    const float* __restrict__ We3, const float* __restrict__ be3,
    const float* __restrict__ Wo1, const float* __restrict__ bo1,
    const float* __restrict__ Wo2, const float* __restrict__ bo2,
    const float* __restrict__ Wd,  const float* __restrict__ bd,
    float* __restrict__ out)
{
  const int t   = blockIdx.x * 256 + threadIdx.x;
  const int b   = t >> 4;
  const int sub = t & 15;

  const float* xb = x + (size_t)b * 2304;
  float xv[9];
#pragma unroll
  for (int i = 0; i < 9; ++i) xv[i] = xb[i];

  const int c0 = sub * 4;
  float s0 = be2[c0+0], s1 = be2[c0+1], s2 = be2[c0+2], s3 = be2[c0+3];
#pragma unroll 4
  for (int i = 0; i < 64; ++i) {
    float h = be1[i];
#pragma unroll
    for (int j = 0; j < 9; ++j) h = fmaf(xv[j], We1[j*64 + i], h);
    h = fmaxf(h, 0.0f);
    const float* w2r = We2 + i*64 + c0;
    s0 = fmaf(h, w2r[0], s0);
    s1 = fmaf(h, w2r[1], s1);
    s2 = fmaf(h, w2r[2], s2);
    s3 = fmaf(h, w2r[3], s3);
  }
  s0 = fmaxf(s0, 0.0f); s1 = fmaxf(s1, 0.0f);
  s2 = fmaxf(s2, 0.0f); s3 = fmaxf(s3, 0.0f);
  float z0a = fmaf(s0, We3[(c0+0)*2+0], fmaf(s1, We3[(c0+1)*2+0],
              fmaf(s2, We3[(c0+2)*2+0],      s3 * We3[(c0+3)*2+0])));
  float z0b = fmaf(s0, We3[(c0+0)*2+1], fmaf(s1, We3[(c0+1)*2+1],
              fmaf(s2, We3[(c0+2)*2+1],      s3 * We3[(c0+3)*2+1])));
  z0a = allred16(z0a) + be3[0];
  z0b = allred16(z0b) + be3[1];

  if (sub == 5) {
    float2 v; v.x = z0a; v.y = z0b;
    *reinterpret_cast<float2*>(out + (size_t)b * 2) = v;
  }

  float* __restrict__ zt = out + 32768;
  float* __restrict__ xh = out + 32768 + 8388608;

  const int r     = sub % 5;
  const int slot0 = (sub < 15) ? (sub / 5) : (1 << 20);
  float ca = 0.f, cb = 0.f, cc = 0.f;
  if      (r == 0) { ca = 1.f; }
  else if (r == 1) { cb = 1.f; }
  else if (r == 2) { ca = Wd[0]; cb = Wd[3]; cc = bd[0]; }
  else if (r == 3) { ca = Wd[1]; cb = Wd[4]; cc = bd[1]; }
  else             { ca = Wd[2]; cb = Wd[5]; cc = bd[2]; }
  float* pbase = (r < 2) ? (zt + (size_t)b * 2 + r)
                         : (xh + (size_t)b * 3 + (r - 2));
  const uint32_t pstride  = (r < 2) ? 32768u : 49152u;
  const uint32_t pstride3 = 3u * pstride;

  if (sub < 5) pbase[0] = fmaf(z0a, ca, fmaf(z0b, cb, cc));

  float w1a[2], w1b[2], b1s[2], w2a[2], w2b[2];
  const int u0 = sub * 2;
#pragma unroll
  for (int q = 0; q < 2; ++q) {
    w1a[q] = Wo1[      u0 + q] * SCALE;
    w1b[q] = Wo1[32 +  u0 + q] * SCALE;
    b1s[q] = bo1[      u0 + q] * SCALE;
    w2a[q] = Wo2[(u0 + q)*2 + 0];
    w2b[q] = Wo2[(u0 + q)*2 + 1];
  }
  const float a0i = (sub == 0) ? bo2[0] : 0.0f;
  const float a1i = (sub == 0) ? bo2[1] : 0.0f;

  auto vf = [&](float za, float zb, float& o0, float& o1) {
    float a0 = a0i, a1 = a1i;
#pragma unroll
    for (int q = 0; q < 2; ++q) {
      float u  = fmaf(za, w1a[q], fmaf(zb, w1b[q], b1s[q]));
      float e  = fast_exp2(u);
      float rr = fast_rcp(e + 1.0f);
      float th = fmaf(-2.0f, rr, 1.0f);
      a0 = fmaf(th, w2a[q], a0);
      a1 = fmaf(th, w2b[q], a1);
    }
    o0 = allred16(a0);
    o1 = allred16(a1);
  };

  float pC0 = 0.f, pC1 = 0.f, pC2 = 0.f, pC3 = 0.f, pkneg = 0.f;
  int   pim0 = 0, pml = -1;
  uint32_t poff = 0;

  auto emit4 = [&](int jb) {
#pragma unroll
    for (int j = 0; j < 4; ++j) {
      const int im = pim0 + 3 * (jb + j);
      if (im <= pml) {
        const float th = fmaf((float)im, K255, pkneg);
        pbase[poff + (uint32_t)(jb + j) * pstride3] =
            fmaf(fmaf(fmaf(pC3, th, pC2), th, pC1), th, pC0);
      }
    }
  };

  float za = z0a, zb = z0b;
  float fa, fb;
  vf(za, zb, fa, fb);

#pragma unroll 1
  for (int k = 0; k < NSEG; ++k) {
    float k2a, k2b, k3a, k3b, k4a, k4b, fna, fnb;
    vf(fmaf(DT2, fa,  za), fmaf(DT2, fb,  zb), k2a, k2b);
    emit4(0);
    vf(fmaf(DT2, k2a, za), fmaf(DT2, k2b, zb), k3a, k3b);
    emit4(4);
    vf(fmaf(DT,  k3a, za), fmaf(DT,  k3b, zb), k4a, k4b);
    float zna = fmaf(DT6, fa + k4a + 2.0f*(k2a + k3a), za);
    float znb = fmaf(DT6, fb + k4b + 2.0f*(k2b + k3b), zb);
    vf(zna, znb, fna, fnb);

    const float da_ = zna - za, db_ = znb - zb;
    const float D  = fmaf(ca, da_, cb * db_);
    pC1 = DT * fmaf(ca, fa,  cb * fb);
    const float Fn = DT * fmaf(ca, fna, cb * fnb);
    pC2 = fmaf(3.f, D, -fmaf(2.f, pC1, Fn));
    pC3 = fmaf(-2.f, D, pC1 + Fn);
    pC0 = fmaf(ca, za, fmaf(cb, zb, cc));
    const int m0 = (255 * k) / NSEG + 1;
    pml  = (255 * (k + 1)) / NSEG;
    pim0 = m0 + slot0;
    pkneg = -(float)k;
    poff  = (uint32_t)pim0 * pstride;

    za = zna; zb = znb; fa = fna; fb = fnb;
  }
  emit4(0);
  emit4(4);
}

extern "C" void kernel_launch(void* const* d_in, const int* in_sizes, int n_in,
                              void* d_out, int out_size, void* d_ws, size_t ws_size,
                              hipStream_t stream)
{
  const float* x   = (const float*)d_in[0];
  const float* We1 = (const float*)d_in[1];
  const float* be1 = (const float*)d_in[2];
  const float* We2 = (const float*)d_in[3];
  const float* be2 = (const float*)d_in[4];
  const float* We3 = (const float*)d_in[5];
  const float* be3 = (const float*)d_in[6];
  const float* Wo1 = (const float*)d_in[7];
  const float* bo1 = (const float*)d_in[8];
  const float* Wo2 = (const float*)d_in[9];
  const float* bo2 = (const float*)d_in[10];
  const float* Wd  = (const float*)d_in[11];
  const float* bd  = (const float*)d_in[12];

  const size_t need = (size_t)(NSEG + 1) * BATCH * sizeof(float4);
  if (ws_size >= need) {
    float4* bnd = (float4*)d_ws;
    dim3 gA(BATCH * 16 / 256), blk(256);
    gait_integrate<<<gA, blk, 0, stream>>>(x, We1, be1, We2, be2, We3, be3,
                                           Wo1, bo1, Wo2, bo2,
                                           (float*)d_out, bnd);
    dim3 gB(256 * BATCH / 256);
    gait_emit<<<gB, blk, 0, stream>>>(bnd, Wd, bd, (float*)d_out);
  } else {
    dim3 gA(BATCH * 16 / 256), blk(256);
    gait_fused<<<gA, blk, 0, stream>>>(x, We1, be1, We2, be2, We3, be3,
                                       Wo1, bo1, Wo2, bo2, Wd, bd,
                                       (float*)d_out);
  }
}